// Round 1
// baseline (21250.438 us; speedup 1.0000x reference)
//
#include <hip/hip_runtime.h>
#include <cmath>

// ---------------- bf16 helpers ----------------
__device__ __forceinline__ float bflo(unsigned int u) {
  union { unsigned int i; float f; } v; v.i = u << 16; return v.f;
}
__device__ __forceinline__ float bfhi(unsigned int u) {
  union { unsigned int i; float f; } v; v.i = u & 0xffff0000u; return v.f;
}
__device__ __forceinline__ float bf2f(unsigned short u) {
  union { unsigned int i; float f; } v; v.i = ((unsigned int)u) << 16; return v.f;
}
__device__ __forceinline__ unsigned short f2bf(float f) {
  union { float f; unsigned int i; } v; v.f = f;
  unsigned int i = v.i;
  return (unsigned short)((i + 0x7fffu + ((i >> 16) & 1u)) >> 16);  // RNE
}

// ---------------- generic tiled GEMM: C[M,N] = act(A[M,K] @ W[N,K]^T + bias) ----------------
#define BM 64
#define BN 64
#define BK 16

__device__ __forceinline__ void load4(const float* p, float* o) {
  float4 v = *reinterpret_cast<const float4*>(p);
  o[0] = v.x; o[1] = v.y; o[2] = v.z; o[3] = v.w;
}
__device__ __forceinline__ void load4(const unsigned short* p, float* o) {
  uint2 v = *reinterpret_cast<const uint2*>(p);
  o[0] = bflo(v.x); o[1] = bfhi(v.x); o[2] = bflo(v.y); o[3] = bfhi(v.y);
}
__device__ __forceinline__ void store1(float* p, float v) { *p = v; }
__device__ __forceinline__ void store1(unsigned short* p, float v) { *p = f2bf(v); }

template <typename TA, typename TC>
__global__ __launch_bounds__(256) void gemm_tile(
    const TA* __restrict__ A, int lda,
    const float* __restrict__ W, int ldw,
    const float* __restrict__ bias,
    TC* __restrict__ C, int ldc,
    int M, int N, int K, int act)
{
  __shared__ float As[BK][BM + 4];
  __shared__ float Bs[BK][BN + 4];
  const int tid = threadIdx.x;
  const int bm = blockIdx.x * BM;
  const int bn = blockIdx.y * BN;
  const int lr = tid & 63;          // load row within tile
  const int lk = (tid >> 6) << 2;   // load k offset (4 elems)
  const int tm = (tid >> 4) << 2;   // compute micro-tile row
  const int tn = (tid & 15) << 2;   // compute micro-tile col
  float acc[4][4] = {};
  const bool aok = (bm + lr) < M;
  const bool wok = (bn + lr) < N;
  const TA* Arow = A + (size_t)(bm + lr) * lda;
  const float* Wrow = W + (size_t)(bn + lr) * ldw;
  for (int k0 = 0; k0 < K; k0 += BK) {
    float af[4] = {0.f, 0.f, 0.f, 0.f};
    float wf[4] = {0.f, 0.f, 0.f, 0.f};
    if (aok) load4(Arow + k0 + lk, af);
    if (wok) load4(Wrow + k0 + lk, wf);
    As[lk + 0][lr] = af[0]; As[lk + 1][lr] = af[1]; As[lk + 2][lr] = af[2]; As[lk + 3][lr] = af[3];
    Bs[lk + 0][lr] = wf[0]; Bs[lk + 1][lr] = wf[1]; Bs[lk + 2][lr] = wf[2]; Bs[lk + 3][lr] = wf[3];
    __syncthreads();
#pragma unroll
    for (int kk = 0; kk < BK; ++kk) {
      float a0 = As[kk][tm + 0], a1 = As[kk][tm + 1], a2 = As[kk][tm + 2], a3 = As[kk][tm + 3];
      float b0 = Bs[kk][tn + 0], b1 = Bs[kk][tn + 1], b2 = Bs[kk][tn + 2], b3 = Bs[kk][tn + 3];
      acc[0][0] = fmaf(a0, b0, acc[0][0]); acc[0][1] = fmaf(a0, b1, acc[0][1]);
      acc[0][2] = fmaf(a0, b2, acc[0][2]); acc[0][3] = fmaf(a0, b3, acc[0][3]);
      acc[1][0] = fmaf(a1, b0, acc[1][0]); acc[1][1] = fmaf(a1, b1, acc[1][1]);
      acc[1][2] = fmaf(a1, b2, acc[1][2]); acc[1][3] = fmaf(a1, b3, acc[1][3]);
      acc[2][0] = fmaf(a2, b0, acc[2][0]); acc[2][1] = fmaf(a2, b1, acc[2][1]);
      acc[2][2] = fmaf(a2, b2, acc[2][2]); acc[2][3] = fmaf(a2, b3, acc[2][3]);
      acc[3][0] = fmaf(a3, b0, acc[3][0]); acc[3][1] = fmaf(a3, b1, acc[3][1]);
      acc[3][2] = fmaf(a3, b2, acc[3][2]); acc[3][3] = fmaf(a3, b3, acc[3][3]);
    }
    __syncthreads();
  }
#pragma unroll
  for (int i = 0; i < 4; ++i) {
    int m = bm + tm + i;
    if (m >= M) continue;
#pragma unroll
    for (int j = 0; j < 4; ++j) {
      int n = bn + tn + j;
      if (n >= N) continue;
      float v = acc[i][j];
      if (bias) v += bias[n];
      if (act == 1) v = 0.5f * v * (1.f + erff(v * 0.70710678f));  // exact GELU
      store1(C + (size_t)m * ldc + n, v);
    }
  }
}

// ---------------- wave reductions ----------------
__device__ __forceinline__ float wred_max(float v) {
#pragma unroll
  for (int off = 32; off > 0; off >>= 1) v = fmaxf(v, __shfl_xor(v, off, 64));
  return v;
}
__device__ __forceinline__ float wred_sum(float v) {
#pragma unroll
  for (int off = 32; off > 0; off >>= 1) v += __shfl_xor(v, off, 64);
  return v;
}

// ---------------- fused attention (online softmax, add_zero_attn absorbed in init m=0,l=1) ----
// one wave per (bg, h, q-row); lane = key index in tile (score phase) / dim d (PV phase)
__global__ __launch_bounds__(256) void attn_kernel(
    const unsigned short* __restrict__ Q, int qstride,
    const unsigned short* __restrict__ Kp,
    const unsigned short* __restrict__ Vp, int kvs,
    float* __restrict__ O, int ostride,
    int kLen,
    const int* __restrict__ tt, const int* __restrict__ ut,
    const unsigned char* __restrict__ kmask,
    const float* __restrict__ rel)   // rpe[l] base, [32][8], or null
{
  const int bg = blockIdx.x >> 3;
  const int h = blockIdx.x & 7;
  const int wave = threadIdx.x >> 6;
  const int lane = threadIdx.x & 63;
  const int q = blockIdx.y * 4 + wave;
  __shared__ __align__(16) float qs[4][64];
  qs[wave][lane] = bf2f(Q[(size_t)(bg * 60 + q) * qstride + h * 64 + lane]);
  __syncthreads();
  const float4* q4 = reinterpret_cast<const float4*>(&qs[wave][0]);
  const int tq = ut ? ut[bg * 60 + q] : 0;
  float m = 0.f, l = 1.f, acc = 0.f;   // zero-attn column: score 0, value 0
  for (int k0 = 0; k0 < kLen; k0 += 64) {
    int kk = k0 + lane;
    float s = -1e30f;
    if (kk < kLen) {
      const uint4* krow = reinterpret_cast<const uint4*>(Kp + ((size_t)bg * kLen + kk) * kvs + h * 64);
      float sum = 0.f;
#pragma unroll
      for (int c = 0; c < 8; ++c) {
        uint4 kv = krow[c];
        float4 qa = q4[2 * c];
        float4 qb = q4[2 * c + 1];
        sum = fmaf(bflo(kv.x), qa.x, sum);
        sum = fmaf(bfhi(kv.x), qa.y, sum);
        sum = fmaf(bflo(kv.y), qa.z, sum);
        sum = fmaf(bfhi(kv.y), qa.w, sum);
        sum = fmaf(bflo(kv.z), qb.x, sum);
        sum = fmaf(bfhi(kv.z), qb.y, sum);
        sum = fmaf(bflo(kv.w), qb.z, sum);
        sum = fmaf(bfhi(kv.w), qb.w, sum);
      }
      s = sum * 0.125f;                                 // 1/sqrt(64)
      if (kmask && kmask[bg * kLen + kk]) s -= 1e30f;   // key padding mask
      if (tt) {                                         // cross-attn bias
        int tk = tt[bg * kLen + kk];
        if (tk >= tq) s -= 1e30f;                       // causal
        s += rel[((tq - tk) & 31) * 8 + h];             // rel PE (python mod 32)
      }
    }
    float nm = fmaxf(m, wred_max(s));
    float p = __expf(s - nm);                           // masked lanes -> 0
    float tsum = wred_sum(p);
    float corr = __expf(m - nm);
    l = l * corr + tsum;
    acc *= corr;
    const unsigned short* vbase = Vp + ((size_t)bg * kLen + k0) * kvs + h * 64 + lane;
    int kmax = min(64, kLen - k0);
    for (int j = 0; j < kmax; ++j) {
      float pj = __shfl(p, j, 64);
      acc = fmaf(pj, bf2f(vbase[(size_t)j * kvs]), acc);
    }
    m = nm;
  }
  O[(size_t)(bg * 60 + q) * ostride + h * 64 + lane] = acc / l;
}

// ---------------- residual add + LayerNorm (E=512) ----------------
__global__ __launch_bounds__(256) void add_ln_kernel(
    const float* __restrict__ a, const float* __restrict__ b,
    const float* __restrict__ g, const float* __restrict__ be,
    float* __restrict__ o)
{
  const int t = blockIdx.x;
  const int tid = threadIdx.x;
  const int wave = tid >> 6, lane = tid & 63;
  const size_t base = (size_t)t * 512;
  float v0 = a[base + tid] + b[base + tid];
  float v1 = a[base + 256 + tid] + b[base + 256 + tid];
  __shared__ float red[4];
  float s = wred_sum(v0 + v1);
  if (lane == 0) red[wave] = s;
  __syncthreads();
  float mean = (red[0] + red[1] + red[2] + red[3]) * (1.0f / 512.0f);
  float d0 = v0 - mean, d1 = v1 - mean;
  float vs = wred_sum(d0 * d0 + d1 * d1);
  __syncthreads();
  if (lane == 0) red[wave] = vs;
  __syncthreads();
  float var = (red[0] + red[1] + red[2] + red[3]) * (1.0f / 512.0f);
  float rstd = rsqrtf(var + 1e-5f);
  o[base + tid] = d0 * rstd * g[tid] + be[tid];
  o[base + 256 + tid] = d1 * rstd * g[256 + tid] + be[256 + tid];
}

// ---------------- embedding builders ----------------
// traj[tok, 0:256]=tf, [256:512]=W_word[:, ids[tok]]  (stored bf16)
__global__ __launch_bounds__(256) void build_traj_kernel(
    const float* __restrict__ tf, const int* __restrict__ ids,
    const float* __restrict__ Ww, unsigned short* __restrict__ traj)
{
  int idx = blockIdx.x * 256 + threadIdx.x;
  int tok = idx >> 9;
  int j = idx & 511;
  float v = (j < 256) ? tf[((size_t)tok << 8) + j] : Ww[(j - 256) * 51 + ids[tok]];
  traj[idx] = f2bf(v);
}

// unk x0[tok, 0:256]=uf, [256:512]=W_word[:, 50]  (fp32 residual stream)
__global__ __launch_bounds__(256) void build_unk_kernel(
    const float* __restrict__ uf, const float* __restrict__ Ww, float* __restrict__ x)
{
  int idx = blockIdx.x * 256 + threadIdx.x;
  int tok = idx >> 9;
  int j = idx & 511;
  x[idx] = (j < 256) ? uf[((size_t)tok << 8) + j] : Ww[(j - 256) * 51 + 50];
}

// ---------------- final head: out[t, n<51] = x[t, 256:512] . W_out[n, :] ----------------
__global__ __launch_bounds__(64) void head_kernel(
    const float* __restrict__ x, const float* __restrict__ Wout, float* __restrict__ out)
{
  const int t = blockIdx.x;
  const int tid = threadIdx.x;
  __shared__ float xs[256];
  for (int i = tid; i < 256; i += 64) xs[i] = x[(size_t)t * 512 + 256 + i];
  __syncthreads();
  if (tid < 51) {
    const float* w = Wout + tid * 256;
    float s = 0.f;
    for (int k = 0; k < 256; ++k) s = fmaf(xs[k], w[k], s);
    out[t * 51 + tid] = s;
  }
}

// ---------------- orchestration ----------------
extern "C" void kernel_launch(void* const* d_in, const int* in_sizes, int n_in,
                              void* d_out, int out_size, void* d_ws, size_t ws_size,
                              hipStream_t stream) {
  const float* tf  = (const float*)d_in[0];
  const float* uf  = (const float*)d_in[1];
  const int*   ids = (const int*)d_in[2];
  const int*   tt  = (const int*)d_in[3];
  const int*   ut  = (const int*)d_in[4];
  const unsigned char* tm = (const unsigned char*)d_in[5];   // all-false bools
  const unsigned char* um = (const unsigned char*)d_in[6];
  const float* Ww   = (const float*)d_in[8];
  const float* Wout = (const float*)d_in[9];
  const float* rpe  = (const float*)d_in[10];
  const float* saW  = (const float*)d_in[11];
  const float* sab  = (const float*)d_in[12];
  const float* saO  = (const float*)d_in[13];
  const float* saob = (const float*)d_in[14];
  const float* sag  = (const float*)d_in[15];
  const float* sabn = (const float*)d_in[16];
  const float* caW  = (const float*)d_in[17];
  const float* cab  = (const float*)d_in[18];
  const float* caO  = (const float*)d_in[19];
  const float* caob = (const float*)d_in[20];
  const float* cag  = (const float*)d_in[21];
  const float* cabn = (const float*)d_in[22];
  const float* f1   = (const float*)d_in[23];
  const float* fb1  = (const float*)d_in[24];
  const float* f2   = (const float*)d_in[25];
  const float* fb2  = (const float*)d_in[26];
  const float* fg   = (const float*)d_in[27];
  const float* fbn  = (const float*)d_in[28];

  // workspace layout (total ~197 MB)
  unsigned short* trajb = (unsigned short*)d_ws;              // 57600*512 bf16
  unsigned short* KVb   = trajb + (size_t)29491200;           // 57600*1024 bf16 (K | V per token)
  unsigned short* qkvb  = KVb + (size_t)58982400;             // 1920*1536 bf16 (self QKV / cross Q)
  float* x    = (float*)(qkvb + (size_t)2949120);             // 1920*512 fp32 residual stream
  float* hbuf = x + (size_t)983040;                           // 1920*2048 fp32 (attn out / ffn hidden)
  float* ybuf = hbuf + (size_t)3932160;                       // 1920*512 fp32

  build_traj_kernel<<<dim3(115200), dim3(256), 0, stream>>>(tf, ids, Ww, trajb);
  build_unk_kernel<<<dim3(3840), dim3(256), 0, stream>>>(uf, Ww, x);

  for (int l = 0; l < 6; ++l) {
    if (l > 0) {
      int sl = l - 1;
      // self-attn QKV: [1920,512] -> [1920,1536] bf16
      gemm_tile<<<dim3(30, 24), dim3(256), 0, stream>>>(
          x, 512, saW + (size_t)sl * 1536 * 512, 512, sab + sl * 1536,
          qkvb, 1536, 1920, 1536, 512, 0);
      attn_kernel<<<dim3(256, 15), dim3(256), 0, stream>>>(
          qkvb, 1536, qkvb + 512, qkvb + 1024, 1536, hbuf, 512, 60,
          (const int*)nullptr, (const int*)nullptr, um, (const float*)nullptr);
      gemm_tile<<<dim3(30, 8), dim3(256), 0, stream>>>(
          hbuf, 512, saO + (size_t)sl * 512 * 512, 512, saob + sl * 512,
          ybuf, 512, 1920, 512, 512, 0);
      add_ln_kernel<<<dim3(1920), dim3(256), 0, stream>>>(x, ybuf, sag + sl * 512, sabn + sl * 512, x);
    }
    // cross-attn K,V projection of full trajectory: [57600,512] -> [57600,1024] bf16
    gemm_tile<<<dim3(900, 16), dim3(256), 0, stream>>>(
        trajb, 512, caW + (size_t)l * 1536 * 512 + 512 * 512, 512, cab + l * 1536 + 512,
        KVb, 1024, 57600, 1024, 512, 0);
    // Q projection: [1920,512] -> [1920,512] bf16
    gemm_tile<<<dim3(30, 8), dim3(256), 0, stream>>>(
        x, 512, caW + (size_t)l * 1536 * 512, 512, cab + l * 1536,
        qkvb, 512, 1920, 512, 512, 0);
    attn_kernel<<<dim3(256, 15), dim3(256), 0, stream>>>(
        qkvb, 512, KVb, KVb + 512, 1024, hbuf, 512, 1800,
        tt, ut, tm, rpe + l * 256);
    gemm_tile<<<dim3(30, 8), dim3(256), 0, stream>>>(
        hbuf, 512, caO + (size_t)l * 512 * 512, 512, caob + l * 512,
        ybuf, 512, 1920, 512, 512, 0);
    add_ln_kernel<<<dim3(1920), dim3(256), 0, stream>>>(x, ybuf, cag + l * 512, cabn + l * 512, x);
    // FFN
    gemm_tile<<<dim3(30, 32), dim3(256), 0, stream>>>(
        x, 512, f1 + (size_t)l * 2048 * 512, 512, fb1 + l * 2048,
        hbuf, 2048, 1920, 2048, 512, 1);
    gemm_tile<<<dim3(30, 8), dim3(256), 0, stream>>>(
        hbuf, 2048, f2 + (size_t)l * 512 * 2048, 2048, fb2 + l * 512,
        ybuf, 512, 1920, 512, 2048, 0);
    add_ln_kernel<<<dim3(1920), dim3(256), 0, stream>>>(x, ybuf, fg + l * 512, fbn + l * 512, x);
  }
  head_kernel<<<dim3(1920), dim3(64), 0, stream>>>(x, Wout, (float*)d_out);
}

// Round 2
// 10519.535 us; speedup vs baseline: 2.0201x; 2.0201x over previous
//
#include <hip/hip_runtime.h>
#include <cmath>

// ---------------- bf16 helpers ----------------
__device__ __forceinline__ float bflo(unsigned int u) {
  union { unsigned int i; float f; } v; v.i = u << 16; return v.f;
}
__device__ __forceinline__ float bfhi(unsigned int u) {
  union { unsigned int i; float f; } v; v.i = u & 0xffff0000u; return v.f;
}
__device__ __forceinline__ float bf2f(unsigned short u) {
  union { unsigned int i; float f; } v; v.i = ((unsigned int)u) << 16; return v.f;
}
__device__ __forceinline__ unsigned short f2bf(float f) {
  union { float f; unsigned int i; } v; v.f = f;
  unsigned int i = v.i;
  return (unsigned short)((i + 0x7fffu + ((i >> 16) & 1u)) >> 16);  // RNE
}

// ---------------- generic tiled GEMM: C[M,N] = act(A[M,K] @ W[N,K]^T + bias) ----------------
#define BM 64
#define BN 64
#define BK 16

__device__ __forceinline__ void load4(const float* p, float* o) {
  float4 v = *reinterpret_cast<const float4*>(p);
  o[0] = v.x; o[1] = v.y; o[2] = v.z; o[3] = v.w;
}
__device__ __forceinline__ void load4(const unsigned short* p, float* o) {
  uint2 v = *reinterpret_cast<const uint2*>(p);
  o[0] = bflo(v.x); o[1] = bfhi(v.x); o[2] = bflo(v.y); o[3] = bfhi(v.y);
}
__device__ __forceinline__ void store1(float* p, float v) { *p = v; }
__device__ __forceinline__ void store1(unsigned short* p, float v) { *p = f2bf(v); }

// tstore=1: C is stored transposed, C[n*ldc + m] (used for K^T layout for attention)
template <typename TA, typename TC>
__global__ __launch_bounds__(256) void gemm_tile(
    const TA* __restrict__ A, int lda,
    const float* __restrict__ W, int ldw,
    const float* __restrict__ bias,
    TC* __restrict__ C, int ldc,
    int M, int N, int K, int act, int tstore)
{
  __shared__ float As[BK][BM + 4];
  __shared__ float Bs[BK][BN + 4];
  const int tid = threadIdx.x;
  const int bm = blockIdx.x * BM;
  const int bn = blockIdx.y * BN;
  const int lr = tid & 63;          // load row within tile
  const int lk = (tid >> 6) << 2;   // load k offset (4 elems)
  const int tm = (tid >> 4) << 2;   // compute micro-tile row
  const int tn = (tid & 15) << 2;   // compute micro-tile col
  float acc[4][4] = {};
  const bool aok = (bm + lr) < M;
  const bool wok = (bn + lr) < N;
  const TA* Arow = A + (size_t)(bm + lr) * lda;
  const float* Wrow = W + (size_t)(bn + lr) * ldw;
  for (int k0 = 0; k0 < K; k0 += BK) {
    float af[4] = {0.f, 0.f, 0.f, 0.f};
    float wf[4] = {0.f, 0.f, 0.f, 0.f};
    if (aok) load4(Arow + k0 + lk, af);
    if (wok) load4(Wrow + k0 + lk, wf);
    As[lk + 0][lr] = af[0]; As[lk + 1][lr] = af[1]; As[lk + 2][lr] = af[2]; As[lk + 3][lr] = af[3];
    Bs[lk + 0][lr] = wf[0]; Bs[lk + 1][lr] = wf[1]; Bs[lk + 2][lr] = wf[2]; Bs[lk + 3][lr] = wf[3];
    __syncthreads();
#pragma unroll
    for (int kk = 0; kk < BK; ++kk) {
      float a0 = As[kk][tm + 0], a1 = As[kk][tm + 1], a2 = As[kk][tm + 2], a3 = As[kk][tm + 3];
      float b0 = Bs[kk][tn + 0], b1 = Bs[kk][tn + 1], b2 = Bs[kk][tn + 2], b3 = Bs[kk][tn + 3];
      acc[0][0] = fmaf(a0, b0, acc[0][0]); acc[0][1] = fmaf(a0, b1, acc[0][1]);
      acc[0][2] = fmaf(a0, b2, acc[0][2]); acc[0][3] = fmaf(a0, b3, acc[0][3]);
      acc[1][0] = fmaf(a1, b0, acc[1][0]); acc[1][1] = fmaf(a1, b1, acc[1][1]);
      acc[1][2] = fmaf(a1, b2, acc[1][2]); acc[1][3] = fmaf(a1, b3, acc[1][3]);
      acc[2][0] = fmaf(a2, b0, acc[2][0]); acc[2][1] = fmaf(a2, b1, acc[2][1]);
      acc[2][2] = fmaf(a2, b2, acc[2][2]); acc[2][3] = fmaf(a2, b3, acc[2][3]);
      acc[3][0] = fmaf(a3, b0, acc[3][0]); acc[3][1] = fmaf(a3, b1, acc[3][1]);
      acc[3][2] = fmaf(a3, b2, acc[3][2]); acc[3][3] = fmaf(a3, b3, acc[3][3]);
    }
    __syncthreads();
  }
#pragma unroll
  for (int i = 0; i < 4; ++i) {
    int m = bm + tm + i;
    if (m >= M) continue;
#pragma unroll
    for (int j = 0; j < 4; ++j) {
      int n = bn + tn + j;
      if (n >= N) continue;
      float v = acc[i][j];
      if (bias) v += bias[n];
      if (act == 1) v = 0.5f * v * (1.f + erff(v * 0.70710678f));  // exact GELU
      if (tstore) store1(C + (size_t)n * ldc + m, v);
      else        store1(C + (size_t)m * ldc + n, v);
    }
  }
}

// ---------------- wave reductions ----------------
__device__ __forceinline__ float wred_max(float v) {
#pragma unroll
  for (int off = 32; off > 0; off >>= 1) v = fmaxf(v, __shfl_xor(v, off, 64));
  return v;
}
__device__ __forceinline__ float wred_sum(float v) {
#pragma unroll
  for (int off = 32; off > 0; off >>= 1) v += __shfl_xor(v, off, 64);
  return v;
}

// ---------------- fused attention v2: q-tiled flash, LDS-staged K/V ----------------
// block = 4 waves, handles (bg, h) x 32 q-rows; wave handles 8 q-rows.
// KT layout: [channel = h*64+d][token = bg*kLen + k]  (written by tstore GEMM)
// V  layout: [token][h*64+d]
// zero-attn column absorbed in init m=0, l=1, acc=0.
#define QPB 32
#define QPW 8
__global__ __launch_bounds__(256) void attn2_kernel(
    const unsigned short* __restrict__ Qp, int qs,
    const unsigned short* __restrict__ KT, int kts,
    const unsigned short* __restrict__ Vp, int vs,
    float* __restrict__ O, int os, int kLen,
    const int* __restrict__ tt, const int* __restrict__ ut,
    const unsigned char* __restrict__ kmask,
    const float* __restrict__ rel)   // rpe[l] base [32][8], or null
{
  const int bg = blockIdx.x >> 3;
  const int h  = blockIdx.x & 7;
  const int q0 = blockIdx.y * QPB;
  const int tid = threadIdx.x;
  const int wave = tid >> 6, lane = tid & 63;

  __shared__ float Qs[QPB][68];
  __shared__ float Ks[64][68];   // Ks[d][k]
  __shared__ float Vs[64][68];   // Vs[k][d]
  __shared__ float Ps[QPB][68];

  // stage Q rows (bf16 -> fp32)
  {
    int qr = tid >> 3, j = tid & 7;
    int q = q0 + qr;
    float f[8] = {0,0,0,0,0,0,0,0};
    if (q < 60) {
      uint4 v = *reinterpret_cast<const uint4*>(Qp + (size_t)(bg * 60 + q) * qs + h * 64 + j * 8);
      f[0]=bflo(v.x); f[1]=bfhi(v.x); f[2]=bflo(v.y); f[3]=bfhi(v.y);
      f[4]=bflo(v.z); f[5]=bfhi(v.z); f[6]=bflo(v.w); f[7]=bfhi(v.w);
    }
#pragma unroll
    for (int e = 0; e < 8; ++e) Qs[qr][j * 8 + e] = f[e];
  }

  // per-lane copy of this head's rel-PE row (index mod 32); gathered via bpermute
  float relreg = 0.f;
  if (rel) relreg = rel[(lane & 31) * 8 + h];

  int tq[QPW];
#pragma unroll
  for (int i = 0; i < QPW; ++i) {
    int q = q0 + wave * QPW + i;
    tq[i] = (ut && q < 60) ? ut[bg * 60 + q] : 0;
  }

  float m[QPW], l[QPW], acc[QPW];
#pragma unroll
  for (int i = 0; i < QPW; ++i) { m[i] = 0.f; l[i] = 1.f; acc[i] = 0.f; }

  const int kd = tid >> 2;        // staging row (d for K, k for V)
  const int kj = tid & 3;

  for (int k0 = 0; k0 < kLen; k0 += 64) {
    __syncthreads();   // prior PV done reading Vs / Qs ready (iter 0)
    // ---- stage K tile transposed: Ks[d][k], uint2 (8B, alignment-safe for kLen%4==0)
    {
      const unsigned short* kb = KT + (size_t)(h * 64 + kd) * kts + (size_t)bg * kLen + k0;
#pragma unroll
      for (int c = 0; c < 4; ++c) {
        int ko = c * 16 + kj * 4;
        float f0 = 0.f, f1 = 0.f, f2 = 0.f, f3 = 0.f;
        if (k0 + ko < kLen) {
          uint2 v = *reinterpret_cast<const uint2*>(kb + ko);
          f0 = bflo(v.x); f1 = bfhi(v.x); f2 = bflo(v.y); f3 = bfhi(v.y);
        }
        Ks[kd][ko + 0] = f0; Ks[kd][ko + 1] = f1; Ks[kd][ko + 2] = f2; Ks[kd][ko + 3] = f3;
      }
    }
    // ---- stage V tile: Vs[k][d]
    {
      bool vok = (k0 + kd) < kLen;
      const unsigned short* vb = Vp + ((size_t)bg * kLen + k0 + kd) * vs + h * 64;
#pragma unroll
      for (int c = 0; c < 2; ++c) {
        int off = c * 32 + kj * 8;
        float f[8] = {0,0,0,0,0,0,0,0};
        if (vok) {
          uint4 v = *reinterpret_cast<const uint4*>(vb + off);
          f[0]=bflo(v.x); f[1]=bfhi(v.x); f[2]=bflo(v.y); f[3]=bfhi(v.y);
          f[4]=bflo(v.z); f[5]=bfhi(v.z); f[6]=bflo(v.w); f[7]=bfhi(v.w);
        }
#pragma unroll
        for (int e = 0; e < 8; ++e) Vs[kd][off + e] = f[e];
      }
    }
    // ---- per-lane key metadata
    const int kk = k0 + lane;
    const bool kok = kk < kLen;
    int tk = 0; unsigned char km = 0;
    if (kok) {
      if (tt) tk = tt[(size_t)bg * kLen + kk];
      if (kmask) km = kmask[(size_t)bg * kLen + kk];
    }
    __syncthreads();

    // ---- QK^T: lane = key, loop d, 8 q accumulators
    float s[QPW];
#pragma unroll
    for (int i = 0; i < QPW; ++i) s[i] = 0.f;
    for (int d = 0; d < 64; ++d) {
      float kv = Ks[d][lane];
#pragma unroll
      for (int i = 0; i < QPW; ++i)
        s[i] = fmaf(Qs[wave * QPW + i][d], kv, s[i]);
    }

    const int kmax = min(64, kLen - k0);
    // ---- softmax update + write P rows (wave-private LDS rows)
#pragma unroll
    for (int i = 0; i < QPW; ++i) {
      float sv = s[i] * 0.125f;            // 1/sqrt(64)
      if (tt) {
        int r = (tq[i] - tk) & 31;         // python mod 32 wrap
        float rv = __int_as_float(__builtin_amdgcn_ds_bpermute(r << 2, __float_as_int(relreg)));
        sv += rv;
        if (tk >= tq[i]) sv = -1e30f;      // causal
      }
      if (km) sv = -1e30f;                 // key padding mask
      if (!kok) sv = -1e30f;               // tile tail
      float nm = fmaxf(m[i], wred_max(sv));
      float p = __expf(sv - nm);
      float ts = wred_sum(p);
      float corr = __expf(m[i] - nm);
      l[i] = l[i] * corr + ts;
      acc[i] *= corr;
      m[i] = nm;
      Ps[wave * QPW + i][lane] = p;
    }
    // ---- PV: lane = dim, loop k, P broadcast
    for (int k = 0; k < kmax; ++k) {
      float v = Vs[k][lane];
#pragma unroll
      for (int i = 0; i < QPW; ++i)
        acc[i] = fmaf(Ps[wave * QPW + i][k], v, acc[i]);
    }
  }

#pragma unroll
  for (int i = 0; i < QPW; ++i) {
    int q = q0 + wave * QPW + i;
    if (q < 60)
      O[(size_t)(bg * 60 + q) * os + h * 64 + lane] = acc[i] / l[i];
  }
}

// ---------------- residual add + LayerNorm (E=512) ----------------
__global__ __launch_bounds__(256) void add_ln_kernel(
    const float* __restrict__ a, const float* __restrict__ b,
    const float* __restrict__ g, const float* __restrict__ be,
    float* __restrict__ o)
{
  const int t = blockIdx.x;
  const int tid = threadIdx.x;
  const int wave = tid >> 6, lane = tid & 63;
  const size_t base = (size_t)t * 512;
  float v0 = a[base + tid] + b[base + tid];
  float v1 = a[base + 256 + tid] + b[base + 256 + tid];
  __shared__ float red[4];
  float s = wred_sum(v0 + v1);
  if (lane == 0) red[wave] = s;
  __syncthreads();
  float mean = (red[0] + red[1] + red[2] + red[3]) * (1.0f / 512.0f);
  float d0 = v0 - mean, d1 = v1 - mean;
  float vs = wred_sum(d0 * d0 + d1 * d1);
  __syncthreads();
  if (lane == 0) red[wave] = vs;
  __syncthreads();
  float var = (red[0] + red[1] + red[2] + red[3]) * (1.0f / 512.0f);
  float rstd = rsqrtf(var + 1e-5f);
  o[base + tid] = d0 * rstd * g[tid] + be[tid];
  o[base + 256 + tid] = d1 * rstd * g[256 + tid] + be[256 + tid];
}

// ---------------- embedding builders ----------------
__global__ __launch_bounds__(256) void build_traj_kernel(
    const float* __restrict__ tf, const int* __restrict__ ids,
    const float* __restrict__ Ww, unsigned short* __restrict__ traj)
{
  int idx = blockIdx.x * 256 + threadIdx.x;
  int tok = idx >> 9;
  int j = idx & 511;
  float v = (j < 256) ? tf[((size_t)tok << 8) + j] : Ww[(j - 256) * 51 + ids[tok]];
  traj[idx] = f2bf(v);
}

__global__ __launch_bounds__(256) void build_unk_kernel(
    const float* __restrict__ uf, const float* __restrict__ Ww, float* __restrict__ x)
{
  int idx = blockIdx.x * 256 + threadIdx.x;
  int tok = idx >> 9;
  int j = idx & 511;
  x[idx] = (j < 256) ? uf[((size_t)tok << 8) + j] : Ww[(j - 256) * 51 + 50];
}

// ---------------- final head ----------------
__global__ __launch_bounds__(64) void head_kernel(
    const float* __restrict__ x, const float* __restrict__ Wout, float* __restrict__ out)
{
  const int t = blockIdx.x;
  const int tid = threadIdx.x;
  __shared__ float xs[256];
  for (int i = tid; i < 256; i += 64) xs[i] = x[(size_t)t * 512 + 256 + i];
  __syncthreads();
  if (tid < 51) {
    const float* w = Wout + tid * 256;
    float s = 0.f;
    for (int k = 0; k < 256; ++k) s = fmaf(xs[k], w[k], s);
    out[t * 51 + tid] = s;
  }
}

// ---------------- orchestration ----------------
extern "C" void kernel_launch(void* const* d_in, const int* in_sizes, int n_in,
                              void* d_out, int out_size, void* d_ws, size_t ws_size,
                              hipStream_t stream) {
  const float* tf  = (const float*)d_in[0];
  const float* uf  = (const float*)d_in[1];
  const int*   ids = (const int*)d_in[2];
  const int*   tt  = (const int*)d_in[3];
  const int*   ut  = (const int*)d_in[4];
  const unsigned char* tm = (const unsigned char*)d_in[5];
  const unsigned char* um = (const unsigned char*)d_in[6];
  const float* Ww   = (const float*)d_in[8];
  const float* Wout = (const float*)d_in[9];
  const float* rpe  = (const float*)d_in[10];
  const float* saW  = (const float*)d_in[11];
  const float* sab  = (const float*)d_in[12];
  const float* saO  = (const float*)d_in[13];
  const float* saob = (const float*)d_in[14];
  const float* sag  = (const float*)d_in[15];
  const float* sabn = (const float*)d_in[16];
  const float* caW  = (const float*)d_in[17];
  const float* cab  = (const float*)d_in[18];
  const float* caO  = (const float*)d_in[19];
  const float* caob = (const float*)d_in[20];
  const float* cag  = (const float*)d_in[21];
  const float* cabn = (const float*)d_in[22];
  const float* f1   = (const float*)d_in[23];
  const float* fb1  = (const float*)d_in[24];
  const float* f2   = (const float*)d_in[25];
  const float* fb2  = (const float*)d_in[26];
  const float* fg   = (const float*)d_in[27];
  const float* fbn  = (const float*)d_in[28];

  // workspace layout (~206 MB)
  unsigned short* trajb = (unsigned short*)d_ws;         // 57600*512
  unsigned short* KTb   = trajb + (size_t)29491200;      // 512*57600 (K transposed)
  unsigned short* Vb    = KTb   + (size_t)29491200;      // 57600*512
  unsigned short* qkvb  = Vb    + (size_t)29491200;      // 1920*512  (Q)
  unsigned short* sKT   = qkvb  + (size_t)983040;        // 512*1920  (self K^T)
  unsigned short* sVb   = sKT   + (size_t)983040;        // 1920*512  (self V)
  float* x    = (float*)(sVb + (size_t)983040);          // 1920*512 residual
  float* hbuf = x + (size_t)983040;                      // 1920*2048
  float* ybuf = hbuf + (size_t)3932160;                  // 1920*512

  build_traj_kernel<<<dim3(115200), dim3(256), 0, stream>>>(tf, ids, Ww, trajb);
  build_unk_kernel<<<dim3(3840), dim3(256), 0, stream>>>(uf, Ww, x);

  for (int l = 0; l < 6; ++l) {
    if (l > 0) {
      int sl = l - 1;
      // self-attn Q / K^T / V projections: [1920,512] each
      gemm_tile<<<dim3(30, 8), dim3(256), 0, stream>>>(
          x, 512, saW + (size_t)sl * 1536 * 512, 512, sab + sl * 1536,
          qkvb, 512, 1920, 512, 512, 0, 0);
      gemm_tile<<<dim3(30, 8), dim3(256), 0, stream>>>(
          x, 512, saW + (size_t)sl * 1536 * 512 + 512 * 512, 512, sab + sl * 1536 + 512,
          sKT, 1920, 1920, 512, 512, 0, 1);
      gemm_tile<<<dim3(30, 8), dim3(256), 0, stream>>>(
          x, 512, saW + (size_t)sl * 1536 * 512 + 1024 * 512, 512, sab + sl * 1536 + 1024,
          sVb, 512, 1920, 512, 512, 0, 0);
      attn2_kernel<<<dim3(256, 2), dim3(256), 0, stream>>>(
          qkvb, 512, sKT, 1920, sVb, 512, hbuf, 512, 60,
          (const int*)nullptr, (const int*)nullptr, um, (const float*)nullptr);
      gemm_tile<<<dim3(30, 8), dim3(256), 0, stream>>>(
          hbuf, 512, saO + (size_t)sl * 512 * 512, 512, saob + sl * 512,
          ybuf, 512, 1920, 512, 512, 0, 0);
      add_ln_kernel<<<dim3(1920), dim3(256), 0, stream>>>(x, ybuf, sag + sl * 512, sabn + sl * 512, x);
    }
    // cross-attn K^T projection: [57600,512] -> KT[512][57600]
    gemm_tile<<<dim3(900, 8), dim3(256), 0, stream>>>(
        trajb, 512, caW + (size_t)l * 1536 * 512 + 512 * 512, 512, cab + l * 1536 + 512,
        KTb, 57600, 57600, 512, 512, 0, 1);
    // cross-attn V projection: [57600,512]
    gemm_tile<<<dim3(900, 8), dim3(256), 0, stream>>>(
        trajb, 512, caW + (size_t)l * 1536 * 512 + 1024 * 512, 512, cab + l * 1536 + 1024,
        Vb, 512, 57600, 512, 512, 0, 0);
    // Q projection: [1920,512]
    gemm_tile<<<dim3(30, 8), dim3(256), 0, stream>>>(
        x, 512, caW + (size_t)l * 1536 * 512, 512, cab + l * 1536,
        qkvb, 512, 1920, 512, 512, 0, 0);
    attn2_kernel<<<dim3(256, 2), dim3(256), 0, stream>>>(
        qkvb, 512, KTb, 57600, Vb, 512, hbuf, 512, 1800,
        tt, ut, tm, rpe + l * 256);
    gemm_tile<<<dim3(30, 8), dim3(256), 0, stream>>>(
        hbuf, 512, caO + (size_t)l * 512 * 512, 512, caob + l * 512,
        ybuf, 512, 1920, 512, 512, 0, 0);
    add_ln_kernel<<<dim3(1920), dim3(256), 0, stream>>>(x, ybuf, cag + l * 512, cabn + l * 512, x);
    // FFN
    gemm_tile<<<dim3(30, 32), dim3(256), 0, stream>>>(
        x, 512, f1 + (size_t)l * 2048 * 512, 512, fb1 + l * 2048,
        hbuf, 2048, 1920, 2048, 512, 1, 0);
    gemm_tile<<<dim3(30, 8), dim3(256), 0, stream>>>(
        hbuf, 2048, f2 + (size_t)l * 512 * 2048, 2048, fb2 + l * 512,
        ybuf, 512, 1920, 512, 2048, 0, 0);
    add_ln_kernel<<<dim3(1920), dim3(256), 0, stream>>>(x, ybuf, fg + l * 512, fbn + l * 512, x);
  }
  head_kernel<<<dim3(1920), dim3(64), 0, stream>>>(x, Wout, (float*)d_out);
}

// Round 3
// 4023.983 us; speedup vs baseline: 5.2809x; 2.6142x over previous
//
#include <hip/hip_runtime.h>
#include <cmath>

// ---------------- bf16 helpers ----------------
__device__ __forceinline__ float bflo(unsigned int u) {
  union { unsigned int i; float f; } v; v.i = u << 16; return v.f;
}
__device__ __forceinline__ float bfhi(unsigned int u) {
  union { unsigned int i; float f; } v; v.i = u & 0xffff0000u; return v.f;
}
__device__ __forceinline__ float bf2f(unsigned short u) {
  union { unsigned int i; float f; } v; v.i = ((unsigned int)u) << 16; return v.f;
}
__device__ __forceinline__ unsigned short f2bf(float f) {
  union { float f; unsigned int i; } v; v.f = f;
  unsigned int i = v.i;
  return (unsigned short)((i + 0x7fffu + ((i >> 16) & 1u)) >> 16);  // RNE
}

typedef __attribute__((ext_vector_type(8))) short short8;
typedef __attribute__((ext_vector_type(4))) float floatx4;

// ---------------- fp32 -> bf16 weight conversion ----------------
__global__ __launch_bounds__(256) void conv_kernel(
    const float* __restrict__ in, unsigned short* __restrict__ out, int n)
{
  int i = (blockIdx.x * 256 + threadIdx.x) << 2;
  if (i >= n) return;
  float4 v = *reinterpret_cast<const float4*>(in + i);
  ushort4 o;
  o.x = f2bf(v.x); o.y = f2bf(v.y); o.z = f2bf(v.z); o.w = f2bf(v.w);
  *reinterpret_cast<ushort4*>(out + i) = o;
}

// ---------------- MFMA GEMM: C[M,N] = act(A[M,K] @ W[N,K]^T + bias) ----------------
// A, W bf16 row-major (K-contiguous). M,N multiples of 128; K multiple of 32.
// m97 structure: 128x128 tile, BK=32, global_load_lds width=16, 4 waves (2x2),
// each wave 4x4 fragments of 16x16x32. C/D layout: col=lane&15, row=(lane>>4)*4+reg.
__global__ __launch_bounds__(256) void gemm_mfma(
    const unsigned short* __restrict__ A, int lda,
    const unsigned short* __restrict__ W, int ldw,
    const float* __restrict__ bias,
    void* __restrict__ Cv, int ldc,
    int K, int act, int cbf16)
{
  __shared__ __align__(16) unsigned short As[128 * 32];
  __shared__ __align__(16) unsigned short Bs[128 * 32];
  const int tid = threadIdx.x;
  const int wave = tid >> 6, lane = tid & 63;
  const int bm = blockIdx.x * 128, bn = blockIdx.y * 128;
  const int wm = (wave >> 1) << 6, wn = (wave & 1) << 6;

  floatx4 acc[4][4];
#pragma unroll
  for (int i = 0; i < 4; ++i)
#pragma unroll
    for (int j = 0; j < 4; ++j) acc[i][j] = (floatx4){0.f, 0.f, 0.f, 0.f};

  // staging: wave stages rows [wave*32, wave*32+32) of both tiles.
  // lane -> (row = lane>>2, kchunk = lane&3): LDS receives lane-ordered 16B
  // chunks == contiguous row-major [16 rows][32 bf16], matching global layout.
  const int srow = (wave << 5) + (lane >> 2);
  const int scol = (lane & 3) << 3;
  const unsigned short* Ag  = A + (size_t)(bm + srow) * lda + scol;
  const unsigned short* Wg  = W + (size_t)(bn + srow) * ldw + scol;
  const unsigned short* Ag2 = Ag + (size_t)16 * lda;
  const unsigned short* Wg2 = Wg + (size_t)16 * ldw;
  unsigned short* AsW = As + (wave << 5) * 32;
  unsigned short* BsW = Bs + (wave << 5) * 32;

  // fragment read pointers: A[m=lane&15][k=(lane>>4)*8+j] (ds_read_b128)
  const unsigned short* a_rd = As + (size_t)(wm + (lane & 15)) * 32 + ((lane >> 4) << 3);
  const unsigned short* b_rd = Bs + (size_t)(wn + (lane & 15)) * 32 + ((lane >> 4) << 3);

  for (int k0 = 0; k0 < K; k0 += 32) {
    __builtin_amdgcn_global_load_lds(
        (const __attribute__((address_space(1))) unsigned int*)(Ag + k0),
        (__attribute__((address_space(3))) unsigned int*)(AsW), 16, 0, 0);
    __builtin_amdgcn_global_load_lds(
        (const __attribute__((address_space(1))) unsigned int*)(Ag2 + k0),
        (__attribute__((address_space(3))) unsigned int*)(AsW + 16 * 32), 16, 0, 0);
    __builtin_amdgcn_global_load_lds(
        (const __attribute__((address_space(1))) unsigned int*)(Wg + k0),
        (__attribute__((address_space(3))) unsigned int*)(BsW), 16, 0, 0);
    __builtin_amdgcn_global_load_lds(
        (const __attribute__((address_space(1))) unsigned int*)(Wg2 + k0),
        (__attribute__((address_space(3))) unsigned int*)(BsW + 16 * 32), 16, 0, 0);
    __syncthreads();   // drains vmcnt(0) then barrier
    short8 af[4], bf[4];
#pragma unroll
    for (int i = 0; i < 4; ++i) {
      af[i] = *reinterpret_cast<const short8*>(a_rd + (size_t)(i << 4) * 32);
      bf[i] = *reinterpret_cast<const short8*>(b_rd + (size_t)(i << 4) * 32);
    }
#pragma unroll
    for (int i = 0; i < 4; ++i)
#pragma unroll
      for (int j = 0; j < 4; ++j)
        acc[i][j] = __builtin_amdgcn_mfma_f32_16x16x32_bf16(af[i], bf[j], acc[i][j], 0, 0, 0);
    __syncthreads();   // all waves done reading before next-iter overwrite
  }

  const int col0 = lane & 15;
  const int row0 = (lane >> 4) << 2;
#pragma unroll
  for (int i = 0; i < 4; ++i) {
#pragma unroll
    for (int j = 0; j < 4; ++j) {
      int col = bn + wn + (j << 4) + col0;
      float bv = bias ? bias[col] : 0.f;
#pragma unroll
      for (int r = 0; r < 4; ++r) {
        int row = bm + wm + (i << 4) + row0 + r;
        float v = acc[i][j][r] + bv;
        if (act) v = 0.5f * v * (1.f + erff(v * 0.70710678f));  // exact GELU
        if (cbf16) ((unsigned short*)Cv)[(size_t)row * ldc + col] = f2bf(v);
        else       ((float*)Cv)[(size_t)row * ldc + col] = v;
      }
    }
  }
}

// ---------------- wave reductions ----------------
__device__ __forceinline__ float wred_max(float v) {
#pragma unroll
  for (int off = 32; off > 0; off >>= 1) v = fmaxf(v, __shfl_xor(v, off, 64));
  return v;
}
__device__ __forceinline__ float wred_sum(float v) {
#pragma unroll
  for (int off = 32; off > 0; off >>= 1) v += __shfl_xor(v, off, 64);
  return v;
}

// ---------------- fused attention: q-tiled flash, token-major K/V ----------------
// block = 4 waves = (bg,h) x 32 q-rows; wave = 8 q-rows. K staged via LDS
// transpose (2 lanes/bank = free). Output bf16. Zero-attn absorbed: m=0,l=1.
#define QPB 32
#define QPW 8
__global__ __launch_bounds__(256) void attn2_kernel(
    const unsigned short* __restrict__ Qp, int qs,
    const unsigned short* __restrict__ Kp, int ks,
    const unsigned short* __restrict__ Vp, int vs,
    unsigned short* __restrict__ O, int os, int kLen,
    const int* __restrict__ tt, const int* __restrict__ ut,
    const unsigned char* __restrict__ kmask,
    const float* __restrict__ rel)   // rpe[l] base [32][8], or null
{
  const int bg = blockIdx.x >> 3;
  const int h  = blockIdx.x & 7;
  const int q0 = blockIdx.y * QPB;
  const int tid = threadIdx.x;
  const int wave = tid >> 6, lane = tid & 63;

  __shared__ float Qs[QPB][68];
  __shared__ float Ks[64][68];   // Ks[d][k]  (transposed at stage time)
  __shared__ float Vs[64][68];   // Vs[k][d]
  __shared__ float Ps[QPB][68];

  // stage Q rows (bf16 -> fp32)
  {
    int qr = tid >> 3, j = tid & 7;
    int q = q0 + qr;
    float f[8] = {0, 0, 0, 0, 0, 0, 0, 0};
    if (q < 60) {
      uint4 v = *reinterpret_cast<const uint4*>(Qp + (size_t)(bg * 60 + q) * qs + h * 64 + j * 8);
      f[0] = bflo(v.x); f[1] = bfhi(v.x); f[2] = bflo(v.y); f[3] = bfhi(v.y);
      f[4] = bflo(v.z); f[5] = bfhi(v.z); f[6] = bflo(v.w); f[7] = bfhi(v.w);
    }
#pragma unroll
    for (int e = 0; e < 8; ++e) Qs[qr][j * 8 + e] = f[e];
  }

  float relreg = 0.f;
  if (rel) relreg = rel[(lane & 31) * 8 + h];

  int tq[QPW];
#pragma unroll
  for (int i = 0; i < QPW; ++i) {
    int q = q0 + wave * QPW + i;
    tq[i] = (ut && q < 60) ? ut[bg * 60 + q] : 0;
  }

  float m[QPW], l[QPW], acc[QPW];
#pragma unroll
  for (int i = 0; i < QPW; ++i) { m[i] = 0.f; l[i] = 1.f; acc[i] = 0.f; }

  const int std = tid >> 2;       // staging token-in-tile (K and V)
  const int stj = tid & 3;        // 16-elem d-group

  for (int k0 = 0; k0 < kLen; k0 += 64) {
    __syncthreads();   // prior PV done reading / Qs ready (iter 0)
    const bool sok = (k0 + std) < kLen;
    // ---- stage K tile with transpose: Ks[d][k] from token-major rows
    {
      const unsigned short* kb = Kp + ((size_t)bg * kLen + k0 + std) * ks + h * 64 + stj * 16;
      float f[16];
#pragma unroll
      for (int e = 0; e < 16; ++e) f[e] = 0.f;
      if (sok) {
        uint4 v0 = *reinterpret_cast<const uint4*>(kb);
        uint4 v1 = *reinterpret_cast<const uint4*>(kb + 8);
        f[0] = bflo(v0.x); f[1] = bfhi(v0.x); f[2]  = bflo(v0.y); f[3]  = bfhi(v0.y);
        f[4] = bflo(v0.z); f[5] = bfhi(v0.z); f[6]  = bflo(v0.w); f[7]  = bfhi(v0.w);
        f[8] = bflo(v1.x); f[9] = bfhi(v1.x); f[10] = bflo(v1.y); f[11] = bfhi(v1.y);
        f[12] = bflo(v1.z); f[13] = bfhi(v1.z); f[14] = bflo(v1.w); f[15] = bfhi(v1.w);
      }
#pragma unroll
      for (int e = 0; e < 16; ++e) Ks[stj * 16 + e][std] = f[e];
    }
    // ---- stage V tile: Vs[k][d]
    {
      const unsigned short* vb = Vp + ((size_t)bg * kLen + k0 + std) * vs + h * 64;
#pragma unroll
      for (int c = 0; c < 2; ++c) {
        int off = c * 32 + stj * 8;
        float f[8] = {0, 0, 0, 0, 0, 0, 0, 0};
        if (sok) {
          uint4 v = *reinterpret_cast<const uint4*>(vb + off);
          f[0] = bflo(v.x); f[1] = bfhi(v.x); f[2] = bflo(v.y); f[3] = bfhi(v.y);
          f[4] = bflo(v.z); f[5] = bfhi(v.z); f[6] = bflo(v.w); f[7] = bfhi(v.w);
        }
#pragma unroll
        for (int e = 0; e < 8; ++e) Vs[std][off + e] = f[e];
      }
    }
    // ---- per-lane key metadata
    const int kk = k0 + lane;
    const bool kok = kk < kLen;
    int tk = 0; unsigned char km = 0;
    if (kok) {
      if (tt) tk = tt[(size_t)bg * kLen + kk];
      if (kmask) km = kmask[(size_t)bg * kLen + kk];
    }
    __syncthreads();

    // ---- QK^T: lane = key, loop d
    float s[QPW];
#pragma unroll
    for (int i = 0; i < QPW; ++i) s[i] = 0.f;
    for (int d = 0; d < 64; ++d) {
      float kv = Ks[d][lane];
#pragma unroll
      for (int i = 0; i < QPW; ++i)
        s[i] = fmaf(Qs[wave * QPW + i][d], kv, s[i]);
    }

    const int kmax = min(64, kLen - k0);
#pragma unroll
    for (int i = 0; i < QPW; ++i) {
      float sv = s[i] * 0.125f;            // 1/sqrt(64)
      if (tt) {
        int r = (tq[i] - tk) & 31;         // python mod-32 wrap
        float rv = __int_as_float(__builtin_amdgcn_ds_bpermute(r << 2, __float_as_int(relreg)));
        sv += rv;
        if (tk >= tq[i]) sv = -1e30f;      // causal
      }
      if (km) sv = -1e30f;
      if (!kok) sv = -1e30f;
      float nm = fmaxf(m[i], wred_max(sv));
      float p = __expf(sv - nm);
      float ts = wred_sum(p);
      float corr = __expf(m[i] - nm);
      l[i] = l[i] * corr + ts;
      acc[i] *= corr;
      m[i] = nm;
      Ps[wave * QPW + i][lane] = p;
    }
    // ---- PV: lane = dim, loop k
    for (int k = 0; k < kmax; ++k) {
      float v = Vs[k][lane];
#pragma unroll
      for (int i = 0; i < QPW; ++i)
        acc[i] = fmaf(Ps[wave * QPW + i][k], v, acc[i]);
    }
  }

#pragma unroll
  for (int i = 0; i < QPW; ++i) {
    int q = q0 + wave * QPW + i;
    if (q < 60)
      O[(size_t)(bg * 60 + q) * os + h * 64 + lane] = f2bf(acc[i] / l[i]);
  }
}

// ---------------- residual add + LayerNorm (E=512), dual fp32+bf16 out ----------------
__global__ __launch_bounds__(256) void add_ln_kernel(
    const float* __restrict__ a, const float* __restrict__ b,
    const float* __restrict__ g, const float* __restrict__ be,
    float* __restrict__ o, unsigned short* __restrict__ ob)
{
  const int t = blockIdx.x;
  const int tid = threadIdx.x;
  const int wave = tid >> 6, lane = tid & 63;
  const size_t base = (size_t)t * 512;
  float v0 = a[base + tid] + b[base + tid];
  float v1 = a[base + 256 + tid] + b[base + 256 + tid];
  __shared__ float red[4];
  float s = wred_sum(v0 + v1);
  if (lane == 0) red[wave] = s;
  __syncthreads();
  float mean = (red[0] + red[1] + red[2] + red[3]) * (1.0f / 512.0f);
  float d0 = v0 - mean, d1 = v1 - mean;
  float vs = wred_sum(d0 * d0 + d1 * d1);
  __syncthreads();
  if (lane == 0) red[wave] = vs;
  __syncthreads();
  float var = (red[0] + red[1] + red[2] + red[3]) * (1.0f / 512.0f);
  float rstd = rsqrtf(var + 1e-5f);
  float r0 = d0 * rstd * g[tid] + be[tid];
  float r1 = d1 * rstd * g[256 + tid] + be[256 + tid];
  o[base + tid] = r0;
  o[base + 256 + tid] = r1;
  ob[base + tid] = f2bf(r0);
  ob[base + 256 + tid] = f2bf(r1);
}

// ---------------- embedding builders ----------------
__global__ __launch_bounds__(256) void build_traj_kernel(
    const float* __restrict__ tf, const int* __restrict__ ids,
    const float* __restrict__ Ww, unsigned short* __restrict__ traj)
{
  int idx = blockIdx.x * 256 + threadIdx.x;
  int tok = idx >> 9;
  int j = idx & 511;
  float v = (j < 256) ? tf[((size_t)tok << 8) + j] : Ww[(j - 256) * 51 + ids[tok]];
  traj[idx] = f2bf(v);
}

__global__ __launch_bounds__(256) void build_unk_kernel(
    const float* __restrict__ uf, const float* __restrict__ Ww,
    float* __restrict__ x, unsigned short* __restrict__ xb)
{
  int idx = blockIdx.x * 256 + threadIdx.x;
  int tok = idx >> 9;
  int j = idx & 511;
  float v = (j < 256) ? uf[((size_t)tok << 8) + j] : Ww[(j - 256) * 51 + 50];
  x[idx] = v;
  xb[idx] = f2bf(v);
}

// ---------------- final head: out[t, n<51] = x[t, 256:512] . W_out[n, :] ----------------
__global__ __launch_bounds__(64) void head_kernel(
    const float* __restrict__ x, const float* __restrict__ Wout, float* __restrict__ out)
{
  const int t = blockIdx.x;
  const int tid = threadIdx.x;
  __shared__ float xs[256];
  for (int i = tid; i < 256; i += 64) xs[i] = x[(size_t)t * 512 + 256 + i];
  __syncthreads();
  if (tid < 51) {
    const float* w = Wout + tid * 256;
    float s = 0.f;
    for (int k = 0; k < 256; ++k) s = fmaf(xs[k], w[k], s);
    out[t * 51 + tid] = s;
  }
}

// ---------------- orchestration ----------------
extern "C" void kernel_launch(void* const* d_in, const int* in_sizes, int n_in,
                              void* d_out, int out_size, void* d_ws, size_t ws_size,
                              hipStream_t stream) {
  const float* tf  = (const float*)d_in[0];
  const float* uf  = (const float*)d_in[1];
  const int*   ids = (const int*)d_in[2];
  const int*   tt  = (const int*)d_in[3];
  const int*   ut  = (const int*)d_in[4];
  const unsigned char* tm = (const unsigned char*)d_in[5];
  const unsigned char* um = (const unsigned char*)d_in[6];
  const float* Ww   = (const float*)d_in[8];
  const float* Wout = (const float*)d_in[9];
  const float* rpe  = (const float*)d_in[10];
  const float* saW  = (const float*)d_in[11];
  const float* sab  = (const float*)d_in[12];
  const float* saO  = (const float*)d_in[13];
  const float* saob = (const float*)d_in[14];
  const float* sag  = (const float*)d_in[15];
  const float* sabn = (const float*)d_in[16];
  const float* caW  = (const float*)d_in[17];
  const float* cab  = (const float*)d_in[18];
  const float* caO  = (const float*)d_in[19];
  const float* caob = (const float*)d_in[20];
  const float* cag  = (const float*)d_in[21];
  const float* cabn = (const float*)d_in[22];
  const float* f1   = (const float*)d_in[23];
  const float* fb1  = (const float*)d_in[24];
  const float* f2   = (const float*)d_in[25];
  const float* fb2  = (const float*)d_in[26];
  const float* fg   = (const float*)d_in[27];
  const float* fbn  = (const float*)d_in[28];

  // workspace layout (~203 MB)
  unsigned short* trajb = (unsigned short*)d_ws;         // 57600*512 bf16
  unsigned short* KVb   = trajb + (size_t)29491200;      // 57600*1024 bf16 (K|V token-major)
  unsigned short* qkvb  = KVb   + (size_t)58982400;      // 1920*1536 bf16 (self QKV / cross Q)
  unsigned short* hb    = qkvb  + (size_t)2949120;       // 1920*2048 bf16 (attn O / FFN hidden)
  unsigned short* xb    = hb    + (size_t)3932160;       // 1920*512 bf16 residual copy
  unsigned short* wconv = xb    + (size_t)983040;        // 1048576 bf16 weight scratch
  float* x    = (float*)(wconv + (size_t)1048576);       // 1920*512 fp32 residual
  float* ybuf = x + (size_t)983040;                      // 1920*512 fp32

  build_traj_kernel<<<dim3(115200), dim3(256), 0, stream>>>(tf, ids, Ww, trajb);
  build_unk_kernel<<<dim3(3840), dim3(256), 0, stream>>>(uf, Ww, x, xb);

  for (int l = 0; l < 6; ++l) {
    if (l > 0) {
      int sl = l - 1;
      // self-attn fused QKV: [1920,512] @ [1536,512]^T -> [1920,1536] bf16
      conv_kernel<<<dim3(768), dim3(256), 0, stream>>>(saW + (size_t)sl * 786432, wconv, 786432);
      gemm_mfma<<<dim3(15, 12), dim3(256), 0, stream>>>(
          xb, 512, wconv, 512, sab + sl * 1536, qkvb, 1536, 512, 0, 1);
      attn2_kernel<<<dim3(256, 2), dim3(256), 0, stream>>>(
          qkvb, 1536, qkvb + 512, 1536, qkvb + 1024, 1536, hb, 512, 60,
          (const int*)nullptr, (const int*)nullptr, um, (const float*)nullptr);
      conv_kernel<<<dim3(256), dim3(256), 0, stream>>>(saO + (size_t)sl * 262144, wconv, 262144);
      gemm_mfma<<<dim3(15, 4), dim3(256), 0, stream>>>(
          hb, 512, wconv, 512, saob + sl * 512, ybuf, 512, 512, 0, 0);
      add_ln_kernel<<<dim3(1920), dim3(256), 0, stream>>>(x, ybuf, sag + sl * 512, sabn + sl * 512, x, xb);
    }
    // cross-attn K|V: [57600,512] @ [1024,512]^T -> [57600,1024] bf16 token-major
    conv_kernel<<<dim3(512), dim3(256), 0, stream>>>(caW + (size_t)l * 786432 + 262144, wconv, 524288);
    gemm_mfma<<<dim3(450, 8), dim3(256), 0, stream>>>(
        trajb, 512, wconv, 512, cab + l * 1536 + 512, KVb, 1024, 512, 0, 1);
    // cross-attn Q: [1920,512]
    conv_kernel<<<dim3(256), dim3(256), 0, stream>>>(caW + (size_t)l * 786432, wconv, 262144);
    gemm_mfma<<<dim3(15, 4), dim3(256), 0, stream>>>(
        xb, 512, wconv, 512, cab + l * 1536, qkvb, 512, 512, 0, 1);
    attn2_kernel<<<dim3(256, 2), dim3(256), 0, stream>>>(
        qkvb, 512, KVb, 1024, KVb + 512, 1024, hb, 512, 1800,
        tt, ut, tm, rpe + l * 256);
    conv_kernel<<<dim3(256), dim3(256), 0, stream>>>(caO + (size_t)l * 262144, wconv, 262144);
    gemm_mfma<<<dim3(15, 4), dim3(256), 0, stream>>>(
        hb, 512, wconv, 512, caob + l * 512, ybuf, 512, 512, 0, 0);
    add_ln_kernel<<<dim3(1920), dim3(256), 0, stream>>>(x, ybuf, cag + l * 512, cabn + l * 512, x, xb);
    // FFN1 + exact GELU: [1920,512] @ [2048,512]^T -> [1920,2048] bf16
    conv_kernel<<<dim3(1024), dim3(256), 0, stream>>>(f1 + (size_t)l * 1048576, wconv, 1048576);
    gemm_mfma<<<dim3(15, 16), dim3(256), 0, stream>>>(
        xb, 512, wconv, 512, fb1 + l * 2048, hb, 2048, 512, 1, 1);
    // FFN2: [1920,2048] @ [512,2048]^T -> [1920,512] fp32
    conv_kernel<<<dim3(1024), dim3(256), 0, stream>>>(f2 + (size_t)l * 1048576, wconv, 1048576);
    gemm_mfma<<<dim3(15, 4), dim3(256), 0, stream>>>(
        hb, 2048, wconv, 2048, fb2 + l * 512, ybuf, 512, 2048, 0, 0);
    add_ln_kernel<<<dim3(1920), dim3(256), 0, stream>>>(x, ybuf, fg + l * 512, fbn + l * 512, x, xb);
  }
  head_kernel<<<dim3(1920), dim3(64), 0, stream>>>(x, Wout, (float*)d_out);
}

// Round 4
// 2339.517 us; speedup vs baseline: 9.0833x; 1.7200x over previous
//
#include <hip/hip_runtime.h>
#include <cmath>

// ---------------- bf16 helpers ----------------
__device__ __forceinline__ float bflo(unsigned int u) {
  union { unsigned int i; float f; } v; v.i = u << 16; return v.f;
}
__device__ __forceinline__ float bfhi(unsigned int u) {
  union { unsigned int i; float f; } v; v.i = u & 0xffff0000u; return v.f;
}
__device__ __forceinline__ float bf2f(unsigned short u) {
  union { unsigned int i; float f; } v; v.i = ((unsigned int)u) << 16; return v.f;
}
__device__ __forceinline__ unsigned short f2bf(float f) {
  union { float f; unsigned int i; } v; v.f = f;
  unsigned int i = v.i;
  return (unsigned short)((i + 0x7fffu + ((i >> 16) & 1u)) >> 16);  // RNE
}

typedef __attribute__((ext_vector_type(8))) short short8;
typedef __attribute__((ext_vector_type(4))) float floatx4;

// ---------------- fp32 -> bf16 weight conversion ----------------
__global__ __launch_bounds__(256) void conv_kernel(
    const float* __restrict__ in, unsigned short* __restrict__ out, int n)
{
  int i = (blockIdx.x * 256 + threadIdx.x) << 2;
  if (i >= n) return;
  float4 v = *reinterpret_cast<const float4*>(in + i);
  ushort4 o;
  o.x = f2bf(v.x); o.y = f2bf(v.y); o.z = f2bf(v.z); o.w = f2bf(v.w);
  *reinterpret_cast<ushort4*>(out + i) = o;
}

// ---------------- MFMA GEMM: C[M,N] = act(A[M,K] @ W[N,K]^T + bias) ----------------
__global__ __launch_bounds__(256) void gemm_mfma(
    const unsigned short* __restrict__ A, int lda,
    const unsigned short* __restrict__ W, int ldw,
    const float* __restrict__ bias,
    void* __restrict__ Cv, int ldc,
    int K, int act, int cbf16)
{
  __shared__ __align__(16) unsigned short As[128 * 32];
  __shared__ __align__(16) unsigned short Bs[128 * 32];
  const int tid = threadIdx.x;
  const int wave = tid >> 6, lane = tid & 63;
  const int bm = blockIdx.x * 128, bn = blockIdx.y * 128;
  const int wm = (wave >> 1) << 6, wn = (wave & 1) << 6;

  floatx4 acc[4][4];
#pragma unroll
  for (int i = 0; i < 4; ++i)
#pragma unroll
    for (int j = 0; j < 4; ++j) acc[i][j] = (floatx4){0.f, 0.f, 0.f, 0.f};

  const int srow = (wave << 5) + (lane >> 2);
  const int scol = (lane & 3) << 3;
  const unsigned short* Ag  = A + (size_t)(bm + srow) * lda + scol;
  const unsigned short* Wg  = W + (size_t)(bn + srow) * ldw + scol;
  const unsigned short* Ag2 = Ag + (size_t)16 * lda;
  const unsigned short* Wg2 = Wg + (size_t)16 * ldw;
  unsigned short* AsW = As + (wave << 5) * 32;
  unsigned short* BsW = Bs + (wave << 5) * 32;

  const unsigned short* a_rd = As + (size_t)(wm + (lane & 15)) * 32 + ((lane >> 4) << 3);
  const unsigned short* b_rd = Bs + (size_t)(wn + (lane & 15)) * 32 + ((lane >> 4) << 3);

  for (int k0 = 0; k0 < K; k0 += 32) {
    __builtin_amdgcn_global_load_lds(
        (const __attribute__((address_space(1))) unsigned int*)(Ag + k0),
        (__attribute__((address_space(3))) unsigned int*)(AsW), 16, 0, 0);
    __builtin_amdgcn_global_load_lds(
        (const __attribute__((address_space(1))) unsigned int*)(Ag2 + k0),
        (__attribute__((address_space(3))) unsigned int*)(AsW + 16 * 32), 16, 0, 0);
    __builtin_amdgcn_global_load_lds(
        (const __attribute__((address_space(1))) unsigned int*)(Wg + k0),
        (__attribute__((address_space(3))) unsigned int*)(BsW), 16, 0, 0);
    __builtin_amdgcn_global_load_lds(
        (const __attribute__((address_space(1))) unsigned int*)(Wg2 + k0),
        (__attribute__((address_space(3))) unsigned int*)(BsW + 16 * 32), 16, 0, 0);
    __syncthreads();
    short8 af[4], bf[4];
#pragma unroll
    for (int i = 0; i < 4; ++i) {
      af[i] = *reinterpret_cast<const short8*>(a_rd + (size_t)(i << 4) * 32);
      bf[i] = *reinterpret_cast<const short8*>(b_rd + (size_t)(i << 4) * 32);
    }
#pragma unroll
    for (int i = 0; i < 4; ++i)
#pragma unroll
      for (int j = 0; j < 4; ++j)
        acc[i][j] = __builtin_amdgcn_mfma_f32_16x16x32_bf16(af[i], bf[j], acc[i][j], 0, 0, 0);
    __syncthreads();
  }

  const int col0 = lane & 15;
  const int row0 = (lane >> 4) << 2;
#pragma unroll
  for (int i = 0; i < 4; ++i) {
#pragma unroll
    for (int j = 0; j < 4; ++j) {
      int col = bn + wn + (j << 4) + col0;
      float bv = bias ? bias[col] : 0.f;
#pragma unroll
      for (int r = 0; r < 4; ++r) {
        int row = bm + wm + (i << 4) + row0 + r;
        float v = acc[i][j][r] + bv;
        if (act) v = 0.5f * v * (1.f + erff(v * 0.70710678f));  // exact GELU
        if (cbf16) ((unsigned short*)Cv)[(size_t)row * ldc + col] = f2bf(v);
        else       ((float*)Cv)[(size_t)row * ldc + col] = v;
      }
    }
  }
}

// ---------------- wave reductions ----------------
__device__ __forceinline__ float wred_max(float v) {
#pragma unroll
  for (int off = 32; off > 0; off >>= 1) v = fmaxf(v, __shfl_xor(v, off, 64));
  return v;
}
__device__ __forceinline__ float wred_sum(float v) {
#pragma unroll
  for (int off = 32; off > 0; off >>= 1) v += __shfl_xor(v, off, 64);
  return v;
}

// ============ MFMA cross-attention (flash, 2 k-groups, in-block merge) ============
// grid = (bg*8) blocks, 512 threads = 8 waves = 2 k-groups x 4 waves.
// Wave w (in group) owns q-rows [w*16, w*16+16); groups split keys (interleaved
// 64-key tiles); merge via LDS. Zero-attn absorbed in group-0 init m=0,l=1.
#define LDK 72
__global__ __launch_bounds__(512) void attn_mfma_kernel(
    const unsigned short* __restrict__ Qp,   // [bg*60][512] bf16
    const unsigned short* __restrict__ KVb,  // [bg*1800][1024] bf16: K|V
    unsigned short* __restrict__ O,          // [bg*60][512] bf16
    const int* __restrict__ tt, const int* __restrict__ ut,
    const unsigned char* __restrict__ km,
    const float* __restrict__ rel)           // rpe[l]: [32][8]
{
  const int bg = blockIdx.x >> 3, h = blockIdx.x & 7;
  const int tid = threadIdx.x;
  const int grp = tid >> 8;
  const int wave = (tid >> 6) & 3;   // wave index within group
  const int lane = tid & 63;
  const int quad = lane >> 4, mrow = lane & 15;

  __shared__ __align__(16) unsigned short SMEM[6 * 64 * LDK];
  unsigned short* Ks = SMEM + grp * (3 * 64 * LDK);  // [key][d]   ld=LDK
  unsigned short* Vt = Ks + 64 * LDK;                // [d][key]   ld=LDK
  unsigned short* Ps = Vt + 64 * LDK;                // [q][key]   ld=LDK

  // preload Q fragments (A-operand: m=lane&15, k=quad*8+j), d = 64 -> 2 chunks
  const int qa = wave * 16 + mrow;
  const int qc = qa < 60 ? qa : 59;
  const unsigned short* qptr = Qp + (size_t)(bg * 60 + qc) * 512 + h * 64 + quad * 8;
  const short8 af0 = *reinterpret_cast<const short8*>(qptr);
  const short8 af1 = *reinterpret_cast<const short8*>(qptr + 32);

  const float relreg = rel[(lane & 31) * 8 + h];

  int tq[4];
  float m[4], l[4];
  floatx4 acc[4];
#pragma unroll
  for (int r = 0; r < 4; ++r) {
    int qo = wave * 16 + quad * 4 + r;
    tq[r] = ut[bg * 60 + (qo < 60 ? qo : 59)];
    m[r] = grp ? -1e30f : 0.f;
    l[r] = grp ? 0.f : 1.f;
  }
#pragma unroll
  for (int nt = 0; nt < 4; ++nt) acc[nt] = (floatx4){0.f, 0.f, 0.f, 0.f};

  const int sk = tid & 255;
  const int stok = sk >> 2, schk = sk & 3;

  for (int it = 0; it < 15; ++it) {
    const int k0 = (grp + 2 * it) << 6;
    __syncthreads();   // previous tile fully consumed
    // ---- stage K (token-major, b128) + V (transposed, scalar u16)
    {
      const int key = k0 + stok;
      uint4 kr0 = {0,0,0,0}, kr1 = {0,0,0,0}, vr0 = {0,0,0,0}, vr1 = {0,0,0,0};
      if (key < 1800) {
        const unsigned short* kb = KVb + ((size_t)bg * 1800 + key) * 1024 + h * 64 + schk * 16;
        kr0 = *reinterpret_cast<const uint4*>(kb);
        kr1 = *reinterpret_cast<const uint4*>(kb + 8);
        vr0 = *reinterpret_cast<const uint4*>(kb + 512);
        vr1 = *reinterpret_cast<const uint4*>(kb + 520);
      }
      *reinterpret_cast<uint4*>(&Ks[stok * LDK + schk * 16]) = kr0;
      *reinterpret_cast<uint4*>(&Ks[stok * LDK + schk * 16 + 8]) = kr1;
      unsigned int wv[8] = {vr0.x, vr0.y, vr0.z, vr0.w, vr1.x, vr1.y, vr1.z, vr1.w};
#pragma unroll
      for (int e = 0; e < 16; ++e)
        Vt[(schk * 16 + e) * LDK + stok] = (unsigned short)(wv[e >> 1] >> ((e & 1) * 16));
    }
    // ---- per-lane key metadata (lane = key-in-tile)
    int meta = 0x10000;
    {
      int kk = k0 + lane;
      if (kk < 1800) {
        int base = bg * 1800 + kk;
        meta = tt[base] | (km[base] ? 0x10000 : 0);
      }
    }
    __syncthreads();

    // ---- QK^T via MFMA: S[nt] rows=q(quad*4+r), cols=key(nt*16+mrow)
    floatx4 S[4];
#pragma unroll
    for (int nt = 0; nt < 4; ++nt) {
      const unsigned short* kb = Ks + (nt * 16 + mrow) * LDK + quad * 8;
      short8 b0 = *reinterpret_cast<const short8*>(kb);
      short8 b1 = *reinterpret_cast<const short8*>(kb + 32);
      floatx4 s = (floatx4){0.f, 0.f, 0.f, 0.f};
      s = __builtin_amdgcn_mfma_f32_16x16x32_bf16(af0, b0, s, 0, 0, 0);
      s = __builtin_amdgcn_mfma_f32_16x16x32_bf16(af1, b1, s, 0, 0, 0);
      S[nt] = s;
    }
    // ---- bias + masks in C-layout
    int mcol[4];
#pragma unroll
    for (int nt = 0; nt < 4; ++nt)
      mcol[nt] = __builtin_amdgcn_ds_bpermute((nt * 16 + mrow) << 2, meta);
    float sv[4][4];
#pragma unroll
    for (int nt = 0; nt < 4; ++nt) {
      int tk = mcol[nt] & 0xffff;
      int bad0 = mcol[nt] >> 16;
#pragma unroll
      for (int r = 0; r < 4; ++r) {
        float v = S[nt][r] * 0.125f;   // 1/sqrt(64)
        int ridx = (tq[r] - tk) & 31;  // python mod-32 wrap
        v += __int_as_float(__builtin_amdgcn_ds_bpermute(ridx << 2, __float_as_int(relreg)));
        sv[nt][r] = (bad0 | (tk >= tq[r])) ? -1e30f : v;
      }
    }
    // ---- online softmax (reduce over 16 lanes of quad via xor-shuffles)
#pragma unroll
    for (int r = 0; r < 4; ++r) {
      float rm = fmaxf(fmaxf(sv[0][r], sv[1][r]), fmaxf(sv[2][r], sv[3][r]));
#pragma unroll
      for (int d = 1; d < 16; d <<= 1) rm = fmaxf(rm, __shfl_xor(rm, d, 64));
      float nm = fmaxf(m[r], rm);
      float corr = __expf(m[r] - nm);
      float ps = 0.f;
      const int prow = (wave * 16 + quad * 4 + r) * LDK + mrow;
#pragma unroll
      for (int nt = 0; nt < 4; ++nt) {
        float p = __expf(sv[nt][r] - nm);
        ps += p;
        Ps[prow + nt * 16] = f2bf(p);
      }
#pragma unroll
      for (int d = 1; d < 16; d <<= 1) ps += __shfl_xor(ps, d, 64);
      l[r] = l[r] * corr + ps;
      m[r] = nm;
#pragma unroll
      for (int nt = 0; nt < 4; ++nt) acc[nt][r] *= corr;
    }
    // ---- PV via MFMA: A = P (rows q), B = V^T (n = d, k = key)
    const unsigned short* pp = Ps + (wave * 16 + mrow) * LDK + quad * 8;
    short8 a0 = *reinterpret_cast<const short8*>(pp);
    short8 a1 = *reinterpret_cast<const short8*>(pp + 32);
#pragma unroll
    for (int nt = 0; nt < 4; ++nt) {
      const unsigned short* vb = Vt + (nt * 16 + mrow) * LDK + quad * 8;
      short8 b0 = *reinterpret_cast<const short8*>(vb);
      short8 b1 = *reinterpret_cast<const short8*>(vb + 32);
      acc[nt] = __builtin_amdgcn_mfma_f32_16x16x32_bf16(a0, b0, acc[nt], 0, 0, 0);
      acc[nt] = __builtin_amdgcn_mfma_f32_16x16x32_bf16(a1, b1, acc[nt], 0, 0, 0);
    }
  }

  // ---- merge the two k-groups through LDS
  __syncthreads();
  float* MA = (float*)SMEM;                       // [64][68] fp32 acc of group 1
  float* Ml = (float*)(SMEM + 64 * 68 * 2);       // [64]
  float* Ll = Ml + 64;                            // [64]
  if (grp == 1) {
#pragma unroll
    for (int r = 0; r < 4; ++r) {
      int row = wave * 16 + quad * 4 + r;
#pragma unroll
      for (int nt = 0; nt < 4; ++nt)
        MA[row * 68 + nt * 16 + mrow] = acc[nt][r];
      if (mrow == 0) { Ml[row] = m[r]; Ll[row] = l[r]; }
    }
  }
  __syncthreads();
  if (grp == 0) {
#pragma unroll
    for (int r = 0; r < 4; ++r) {
      int row = wave * 16 + quad * 4 + r;
      float m1 = Ml[row], l1 = Ll[row];
      float M = fmaxf(m[r], m1);
      float c0 = __expf(m[r] - M), c1 = __expf(m1 - M);
      float invL = 1.f / (l[r] * c0 + l1 * c1);
      if (row < 60) {
        unsigned short* op = O + (size_t)(bg * 60 + row) * 512 + h * 64;
#pragma unroll
        for (int nt = 0; nt < 4; ++nt) {
          float o = (acc[nt][r] * c0 + MA[row * 68 + nt * 16 + mrow] * c1) * invL;
          op[nt * 16 + mrow] = f2bf(o);
        }
      }
    }
  }
}

// ---------------- VALU flash attention (kept for tiny self-attn, kLen=60) ----------------
#define QPB 32
#define QPW 8
__global__ __launch_bounds__(256) void attn2_kernel(
    const unsigned short* __restrict__ Qp, int qs,
    const unsigned short* __restrict__ Kp, int ks,
    const unsigned short* __restrict__ Vp, int vs,
    unsigned short* __restrict__ O, int os, int kLen,
    const unsigned char* __restrict__ kmask)
{
  const int bg = blockIdx.x >> 3;
  const int h  = blockIdx.x & 7;
  const int q0 = blockIdx.y * QPB;
  const int tid = threadIdx.x;
  const int wave = tid >> 6, lane = tid & 63;

  __shared__ float Qs[QPB][68];
  __shared__ float Ks[64][68];
  __shared__ float Vs[64][68];
  __shared__ float Ps[QPB][68];

  {
    int qr = tid >> 3, j = tid & 7;
    int q = q0 + qr;
    float f[8] = {0, 0, 0, 0, 0, 0, 0, 0};
    if (q < 60) {
      uint4 v = *reinterpret_cast<const uint4*>(Qp + (size_t)(bg * 60 + q) * qs + h * 64 + j * 8);
      f[0] = bflo(v.x); f[1] = bfhi(v.x); f[2] = bflo(v.y); f[3] = bfhi(v.y);
      f[4] = bflo(v.z); f[5] = bfhi(v.z); f[6] = bflo(v.w); f[7] = bfhi(v.w);
    }
#pragma unroll
    for (int e = 0; e < 8; ++e) Qs[qr][j * 8 + e] = f[e];
  }

  float m[QPW], l[QPW], acc[QPW];
#pragma unroll
  for (int i = 0; i < QPW; ++i) { m[i] = 0.f; l[i] = 1.f; acc[i] = 0.f; }

  const int std = tid >> 2;
  const int stj = tid & 3;

  for (int k0 = 0; k0 < kLen; k0 += 64) {
    __syncthreads();
    const bool sok = (k0 + std) < kLen;
    {
      const unsigned short* kb = Kp + ((size_t)bg * kLen + k0 + std) * ks + h * 64 + stj * 16;
      float f[16];
#pragma unroll
      for (int e = 0; e < 16; ++e) f[e] = 0.f;
      if (sok) {
        uint4 v0 = *reinterpret_cast<const uint4*>(kb);
        uint4 v1 = *reinterpret_cast<const uint4*>(kb + 8);
        f[0] = bflo(v0.x); f[1] = bfhi(v0.x); f[2]  = bflo(v0.y); f[3]  = bfhi(v0.y);
        f[4] = bflo(v0.z); f[5] = bfhi(v0.z); f[6]  = bflo(v0.w); f[7]  = bfhi(v0.w);
        f[8] = bflo(v1.x); f[9] = bfhi(v1.x); f[10] = bflo(v1.y); f[11] = bfhi(v1.y);
        f[12] = bflo(v1.z); f[13] = bfhi(v1.z); f[14] = bflo(v1.w); f[15] = bfhi(v1.w);
      }
#pragma unroll
      for (int e = 0; e < 16; ++e) Ks[stj * 16 + e][std] = f[e];
    }
    {
      const unsigned short* vb = Vp + ((size_t)bg * kLen + k0 + std) * vs + h * 64;
#pragma unroll
      for (int c = 0; c < 2; ++c) {
        int off = c * 32 + stj * 8;
        float f[8] = {0, 0, 0, 0, 0, 0, 0, 0};
        if (sok) {
          uint4 v = *reinterpret_cast<const uint4*>(vb + off);
          f[0] = bflo(v.x); f[1] = bfhi(v.x); f[2] = bflo(v.y); f[3] = bfhi(v.y);
          f[4] = bflo(v.z); f[5] = bfhi(v.z); f[6] = bflo(v.w); f[7] = bfhi(v.w);
        }
#pragma unroll
        for (int e = 0; e < 8; ++e) Vs[std][off + e] = f[e];
      }
    }
    const int kk = k0 + lane;
    const bool kok = kk < kLen;
    unsigned char kmv = 0;
    if (kok && kmask) kmv = kmask[(size_t)bg * kLen + kk];
    __syncthreads();

    float s[QPW];
#pragma unroll
    for (int i = 0; i < QPW; ++i) s[i] = 0.f;
    for (int d = 0; d < 64; ++d) {
      float kv = Ks[d][lane];
#pragma unroll
      for (int i = 0; i < QPW; ++i)
        s[i] = fmaf(Qs[wave * QPW + i][d], kv, s[i]);
    }

    const int kmax = min(64, kLen - k0);
#pragma unroll
    for (int i = 0; i < QPW; ++i) {
      float svv = s[i] * 0.125f;
      if (kmv || !kok) svv = -1e30f;
      float nm = fmaxf(m[i], wred_max(svv));
      float p = __expf(svv - nm);
      float ts = wred_sum(p);
      float corr = __expf(m[i] - nm);
      l[i] = l[i] * corr + ts;
      acc[i] *= corr;
      m[i] = nm;
      Ps[wave * QPW + i][lane] = p;
    }
    for (int k = 0; k < kmax; ++k) {
      float v = Vs[k][lane];
#pragma unroll
      for (int i = 0; i < QPW; ++i)
        acc[i] = fmaf(Ps[wave * QPW + i][k], v, acc[i]);
    }
  }

#pragma unroll
  for (int i = 0; i < QPW; ++i) {
    int q = q0 + wave * QPW + i;
    if (q < 60)
      O[(size_t)(bg * 60 + q) * os + h * 64 + lane] = f2bf(acc[i] / l[i]);
  }
}

// ---------------- residual add + LayerNorm (E=512), dual fp32+bf16 out ----------------
__global__ __launch_bounds__(256) void add_ln_kernel(
    const float* __restrict__ a, const float* __restrict__ b,
    const float* __restrict__ g, const float* __restrict__ be,
    float* __restrict__ o, unsigned short* __restrict__ ob)
{
  const int t = blockIdx.x;
  const int tid = threadIdx.x;
  const int wave = tid >> 6, lane = tid & 63;
  const size_t base = (size_t)t * 512;
  float v0 = a[base + tid] + b[base + tid];
  float v1 = a[base + 256 + tid] + b[base + 256 + tid];
  __shared__ float red[4];
  float s = wred_sum(v0 + v1);
  if (lane == 0) red[wave] = s;
  __syncthreads();
  float mean = (red[0] + red[1] + red[2] + red[3]) * (1.0f / 512.0f);
  float d0 = v0 - mean, d1 = v1 - mean;
  float vs = wred_sum(d0 * d0 + d1 * d1);
  __syncthreads();
  if (lane == 0) red[wave] = vs;
  __syncthreads();
  float var = (red[0] + red[1] + red[2] + red[3]) * (1.0f / 512.0f);
  float rstd = rsqrtf(var + 1e-5f);
  float r0 = d0 * rstd * g[tid] + be[tid];
  float r1 = d1 * rstd * g[256 + tid] + be[256 + tid];
  o[base + tid] = r0;
  o[base + 256 + tid] = r1;
  ob[base + tid] = f2bf(r0);
  ob[base + 256 + tid] = f2bf(r1);
}

// ---------------- embedding builders ----------------
__global__ __launch_bounds__(256) void build_traj_kernel(
    const float* __restrict__ tf, const int* __restrict__ ids,
    const float* __restrict__ Ww, unsigned short* __restrict__ traj)
{
  int idx = blockIdx.x * 256 + threadIdx.x;
  int tok = idx >> 9;
  int j = idx & 511;
  float v = (j < 256) ? tf[((size_t)tok << 8) + j] : Ww[(j - 256) * 51 + ids[tok]];
  traj[idx] = f2bf(v);
}

__global__ __launch_bounds__(256) void build_unk_kernel(
    const float* __restrict__ uf, const float* __restrict__ Ww,
    float* __restrict__ x, unsigned short* __restrict__ xb)
{
  int idx = blockIdx.x * 256 + threadIdx.x;
  int tok = idx >> 9;
  int j = idx & 511;
  float v = (j < 256) ? uf[((size_t)tok << 8) + j] : Ww[(j - 256) * 51 + 50];
  x[idx] = v;
  xb[idx] = f2bf(v);
}

// ---------------- final head ----------------
__global__ __launch_bounds__(64) void head_kernel(
    const float* __restrict__ x, const float* __restrict__ Wout, float* __restrict__ out)
{
  const int t = blockIdx.x;
  const int tid = threadIdx.x;
  __shared__ float xs[256];
  for (int i = tid; i < 256; i += 64) xs[i] = x[(size_t)t * 512 + 256 + i];
  __syncthreads();
  if (tid < 51) {
    const float* w = Wout + tid * 256;
    float s = 0.f;
    for (int k = 0; k < 256; ++k) s = fmaf(xs[k], w[k], s);
    out[t * 51 + tid] = s;
  }
}

// ---------------- orchestration ----------------
extern "C" void kernel_launch(void* const* d_in, const int* in_sizes, int n_in,
                              void* d_out, int out_size, void* d_ws, size_t ws_size,
                              hipStream_t stream) {
  const float* tf  = (const float*)d_in[0];
  const float* uf  = (const float*)d_in[1];
  const int*   ids = (const int*)d_in[2];
  const int*   tt  = (const int*)d_in[3];
  const int*   ut  = (const int*)d_in[4];
  const unsigned char* tm = (const unsigned char*)d_in[5];
  const unsigned char* um = (const unsigned char*)d_in[6];
  const float* Ww   = (const float*)d_in[8];
  const float* Wout = (const float*)d_in[9];
  const float* rpe  = (const float*)d_in[10];
  const float* saW  = (const float*)d_in[11];
  const float* sab  = (const float*)d_in[12];
  const float* saO  = (const float*)d_in[13];
  const float* saob = (const float*)d_in[14];
  const float* sag  = (const float*)d_in[15];
  const float* sabn = (const float*)d_in[16];
  const float* caW  = (const float*)d_in[17];
  const float* cab  = (const float*)d_in[18];
  const float* caO  = (const float*)d_in[19];
  const float* caob = (const float*)d_in[20];
  const float* cag  = (const float*)d_in[21];
  const float* cabn = (const float*)d_in[22];
  const float* f1   = (const float*)d_in[23];
  const float* fb1  = (const float*)d_in[24];
  const float* f2   = (const float*)d_in[25];
  const float* fb2  = (const float*)d_in[26];
  const float* fg   = (const float*)d_in[27];
  const float* fbn  = (const float*)d_in[28];

  // workspace layout (~203 MB)
  unsigned short* trajb = (unsigned short*)d_ws;         // 57600*512 bf16
  unsigned short* KVb   = trajb + (size_t)29491200;      // 57600*1024 bf16 (K|V token-major)
  unsigned short* qkvb  = KVb   + (size_t)58982400;      // 1920*1536 bf16 (self QKV / cross Q)
  unsigned short* hb    = qkvb  + (size_t)2949120;       // 1920*2048 bf16 (attn O / FFN hidden)
  unsigned short* xb    = hb    + (size_t)3932160;       // 1920*512 bf16 residual copy
  unsigned short* wconv = xb    + (size_t)983040;        // 1048576 bf16 weight scratch
  float* x    = (float*)(wconv + (size_t)1048576);       // 1920*512 fp32 residual
  float* ybuf = x + (size_t)983040;                      // 1920*512 fp32

  build_traj_kernel<<<dim3(115200), dim3(256), 0, stream>>>(tf, ids, Ww, trajb);
  build_unk_kernel<<<dim3(3840), dim3(256), 0, stream>>>(uf, Ww, x, xb);

  for (int l = 0; l < 6; ++l) {
    if (l > 0) {
      int sl = l - 1;
      conv_kernel<<<dim3(768), dim3(256), 0, stream>>>(saW + (size_t)sl * 786432, wconv, 786432);
      gemm_mfma<<<dim3(15, 12), dim3(256), 0, stream>>>(
          xb, 512, wconv, 512, sab + sl * 1536, qkvb, 1536, 512, 0, 1);
      attn2_kernel<<<dim3(256, 2), dim3(256), 0, stream>>>(
          qkvb, 1536, qkvb + 512, 1536, qkvb + 1024, 1536, hb, 512, 60, um);
      conv_kernel<<<dim3(256), dim3(256), 0, stream>>>(saO + (size_t)sl * 262144, wconv, 262144);
      gemm_mfma<<<dim3(15, 4), dim3(256), 0, stream>>>(
          hb, 512, wconv, 512, saob + sl * 512, ybuf, 512, 512, 0, 0);
      add_ln_kernel<<<dim3(1920), dim3(256), 0, stream>>>(x, ybuf, sag + sl * 512, sabn + sl * 512, x, xb);
    }
    // ca_Wqkv for layer l: one conv covers Q|K|V (contiguous 1536x512)
    conv_kernel<<<dim3(768), dim3(256), 0, stream>>>(caW + (size_t)l * 786432, wconv, 786432);
    // cross-attn K|V: [57600,512] @ [1024,512]^T -> [57600,1024] bf16 token-major
    gemm_mfma<<<dim3(450, 8), dim3(256), 0, stream>>>(
        trajb, 512, wconv + 262144, 512, cab + l * 1536 + 512, KVb, 1024, 512, 0, 1);
    // cross-attn Q: [1920,512]
    gemm_mfma<<<dim3(15, 4), dim3(256), 0, stream>>>(
        xb, 512, wconv, 512, cab + l * 1536, qkvb, 512, 512, 0, 1);
    attn_mfma_kernel<<<dim3(256), dim3(512), 0, stream>>>(
        qkvb, KVb, hb, tt, ut, tm, rpe + l * 256);
    conv_kernel<<<dim3(256), dim3(256), 0, stream>>>(caO + (size_t)l * 262144, wconv, 262144);
    gemm_mfma<<<dim3(15, 4), dim3(256), 0, stream>>>(
        hb, 512, wconv, 512, caob + l * 512, ybuf, 512, 512, 0, 0);
    add_ln_kernel<<<dim3(1920), dim3(256), 0, stream>>>(x, ybuf, cag + l * 512, cabn + l * 512, x, xb);
    // FFN1 + exact GELU
    conv_kernel<<<dim3(1024), dim3(256), 0, stream>>>(f1 + (size_t)l * 1048576, wconv, 1048576);
    gemm_mfma<<<dim3(15, 16), dim3(256), 0, stream>>>(
        xb, 512, wconv, 512, fb1 + l * 2048, hb, 2048, 512, 1, 1);
    // FFN2
    conv_kernel<<<dim3(1024), dim3(256), 0, stream>>>(f2 + (size_t)l * 1048576, wconv, 1048576);
    gemm_mfma<<<dim3(15, 4), dim3(256), 0, stream>>>(
        hb, 2048, wconv, 2048, fb2 + l * 512, ybuf, 512, 2048, 0, 0);
    add_ln_kernel<<<dim3(1920), dim3(256), 0, stream>>>(x, ybuf, fg + l * 512, fbn + l * 512, x, xb);
  }
  head_kernel<<<dim3(1920), dim3(64), 0, stream>>>(x, Wout, (float*)d_out);
}

// Round 5
// 2299.983 us; speedup vs baseline: 9.2394x; 1.0172x over previous
//
#include <hip/hip_runtime.h>
#include <cmath>

// ---------------- bf16 helpers ----------------
__device__ __forceinline__ float bflo(unsigned int u) {
  union { unsigned int i; float f; } v; v.i = u << 16; return v.f;
}
__device__ __forceinline__ float bfhi(unsigned int u) {
  union { unsigned int i; float f; } v; v.i = u & 0xffff0000u; return v.f;
}
__device__ __forceinline__ float bf2f(unsigned short u) {
  union { unsigned int i; float f; } v; v.i = ((unsigned int)u) << 16; return v.f;
}
__device__ __forceinline__ unsigned short f2bf(float f) {
  union { float f; unsigned int i; } v; v.f = f;
  unsigned int i = v.i;
  return (unsigned short)((i + 0x7fffu + ((i >> 16) & 1u)) >> 16);  // RNE
}

typedef __attribute__((ext_vector_type(8))) short short8;
typedef __attribute__((ext_vector_type(4))) float floatx4;

// ---------------- fp32 -> bf16 weight conversion ----------------
__global__ __launch_bounds__(256) void conv_kernel(
    const float* __restrict__ in, unsigned short* __restrict__ out, int n)
{
  int i = (blockIdx.x * 256 + threadIdx.x) << 2;
  if (i >= n) return;
  float4 v = *reinterpret_cast<const float4*>(in + i);
  ushort4 o;
  o.x = f2bf(v.x); o.y = f2bf(v.y); o.z = f2bf(v.z); o.w = f2bf(v.w);
  *reinterpret_cast<ushort4*>(out + i) = o;
}

// ---------------- MFMA GEMM: C[M,N] = act(A[M,K] @ W[N,K]^T + bias) ----------------
// N-fast dispatch: blockIdx.x = N-tile (A-tile reuse window in L2/L3), blockIdx.y = M-tile.
__global__ __launch_bounds__(256) void gemm_mfma(
    const unsigned short* __restrict__ A, int lda,
    const unsigned short* __restrict__ W, int ldw,
    const float* __restrict__ bias,
    void* __restrict__ Cv, int ldc,
    int K, int act, int cbf16)
{
  __shared__ __align__(16) unsigned short As[128 * 32];
  __shared__ __align__(16) unsigned short Bs[128 * 32];
  const int tid = threadIdx.x;
  const int wave = tid >> 6, lane = tid & 63;
  const int bm = blockIdx.y * 128, bn = blockIdx.x * 128;
  const int wm = (wave >> 1) << 6, wn = (wave & 1) << 6;

  floatx4 acc[4][4];
#pragma unroll
  for (int i = 0; i < 4; ++i)
#pragma unroll
    for (int j = 0; j < 4; ++j) acc[i][j] = (floatx4){0.f, 0.f, 0.f, 0.f};

  const int srow = (wave << 5) + (lane >> 2);
  const int scol = (lane & 3) << 3;
  const unsigned short* Ag  = A + (size_t)(bm + srow) * lda + scol;
  const unsigned short* Wg  = W + (size_t)(bn + srow) * ldw + scol;
  const unsigned short* Ag2 = Ag + (size_t)16 * lda;
  const unsigned short* Wg2 = Wg + (size_t)16 * ldw;
  unsigned short* AsW = As + (wave << 5) * 32;
  unsigned short* BsW = Bs + (wave << 5) * 32;

  const unsigned short* a_rd = As + (size_t)(wm + (lane & 15)) * 32 + ((lane >> 4) << 3);
  const unsigned short* b_rd = Bs + (size_t)(wn + (lane & 15)) * 32 + ((lane >> 4) << 3);

  for (int k0 = 0; k0 < K; k0 += 32) {
    __builtin_amdgcn_global_load_lds(
        (const __attribute__((address_space(1))) unsigned int*)(Ag + k0),
        (__attribute__((address_space(3))) unsigned int*)(AsW), 16, 0, 0);
    __builtin_amdgcn_global_load_lds(
        (const __attribute__((address_space(1))) unsigned int*)(Ag2 + k0),
        (__attribute__((address_space(3))) unsigned int*)(AsW + 16 * 32), 16, 0, 0);
    __builtin_amdgcn_global_load_lds(
        (const __attribute__((address_space(1))) unsigned int*)(Wg + k0),
        (__attribute__((address_space(3))) unsigned int*)(BsW), 16, 0, 0);
    __builtin_amdgcn_global_load_lds(
        (const __attribute__((address_space(1))) unsigned int*)(Wg2 + k0),
        (__attribute__((address_space(3))) unsigned int*)(BsW + 16 * 32), 16, 0, 0);
    __syncthreads();
    short8 af[4], bf[4];
#pragma unroll
    for (int i = 0; i < 4; ++i) {
      af[i] = *reinterpret_cast<const short8*>(a_rd + (size_t)(i << 4) * 32);
      bf[i] = *reinterpret_cast<const short8*>(b_rd + (size_t)(i << 4) * 32);
    }
#pragma unroll
    for (int i = 0; i < 4; ++i)
#pragma unroll
      for (int j = 0; j < 4; ++j)
        acc[i][j] = __builtin_amdgcn_mfma_f32_16x16x32_bf16(af[i], bf[j], acc[i][j], 0, 0, 0);
    __syncthreads();
  }

  const int col0 = lane & 15;
  const int row0 = (lane >> 4) << 2;
#pragma unroll
  for (int i = 0; i < 4; ++i) {
#pragma unroll
    for (int j = 0; j < 4; ++j) {
      int col = bn + wn + (j << 4) + col0;
      float bv = bias ? bias[col] : 0.f;
#pragma unroll
      for (int r = 0; r < 4; ++r) {
        int row = bm + wm + (i << 4) + row0 + r;
        float v = acc[i][j][r] + bv;
        if (act) v = 0.5f * v * (1.f + erff(v * 0.70710678f));  // exact GELU
        if (cbf16) ((unsigned short*)Cv)[(size_t)row * ldc + col] = f2bf(v);
        else       ((float*)Cv)[(size_t)row * ldc + col] = v;
      }
    }
  }
}

// ---------------- wave reductions ----------------
__device__ __forceinline__ float wred_max(float v) {
#pragma unroll
  for (int off = 32; off > 0; off >>= 1) v = fmaxf(v, __shfl_xor(v, off, 64));
  return v;
}
__device__ __forceinline__ float wred_sum(float v) {
#pragma unroll
  for (int off = 32; off > 0; off >>= 1) v += __shfl_xor(v, off, 64);
  return v;
}

// ============ MFMA cross-attention (flash, 2 k-groups, in-block merge) ============
#define LDK 72
__global__ __launch_bounds__(512) void attn_mfma_kernel(
    const unsigned short* __restrict__ Qp,   // [bg*60][512] bf16
    const unsigned short* __restrict__ KVb,  // [bg*1800][1024] bf16: K|V
    unsigned short* __restrict__ O,          // [bg*60][512] bf16
    const int* __restrict__ tt, const int* __restrict__ ut,
    const unsigned char* __restrict__ km,
    const float* __restrict__ rel)           // rpe[l]: [32][8]
{
  const int bg = blockIdx.x >> 3, h = blockIdx.x & 7;
  const int tid = threadIdx.x;
  const int grp = tid >> 8;
  const int wave = (tid >> 6) & 3;
  const int lane = tid & 63;
  const int quad = lane >> 4, mrow = lane & 15;

  __shared__ __align__(16) unsigned short SMEM[6 * 64 * LDK];
  unsigned short* Ks = SMEM + grp * (3 * 64 * LDK);
  unsigned short* Vt = Ks + 64 * LDK;
  unsigned short* Ps = Vt + 64 * LDK;

  const int qa = wave * 16 + mrow;
  const int qc = qa < 60 ? qa : 59;
  const unsigned short* qptr = Qp + (size_t)(bg * 60 + qc) * 512 + h * 64 + quad * 8;
  const short8 af0 = *reinterpret_cast<const short8*>(qptr);
  const short8 af1 = *reinterpret_cast<const short8*>(qptr + 32);

  const float relreg = rel[(lane & 31) * 8 + h];

  int tq[4];
  float m[4], l[4];
  floatx4 acc[4];
#pragma unroll
  for (int r = 0; r < 4; ++r) {
    int qo = wave * 16 + quad * 4 + r;
    tq[r] = ut[bg * 60 + (qo < 60 ? qo : 59)];
    m[r] = grp ? -1e30f : 0.f;
    l[r] = grp ? 0.f : 1.f;
  }
#pragma unroll
  for (int nt = 0; nt < 4; ++nt) acc[nt] = (floatx4){0.f, 0.f, 0.f, 0.f};

  const int sk = tid & 255;
  const int stok = sk >> 2, schk = sk & 3;

  for (int it = 0; it < 15; ++it) {
    const int k0 = (grp + 2 * it) << 6;
    __syncthreads();
    {
      const int key = k0 + stok;
      uint4 kr0 = {0,0,0,0}, kr1 = {0,0,0,0}, vr0 = {0,0,0,0}, vr1 = {0,0,0,0};
      if (key < 1800) {
        const unsigned short* kb = KVb + ((size_t)bg * 1800 + key) * 1024 + h * 64 + schk * 16;
        kr0 = *reinterpret_cast<const uint4*>(kb);
        kr1 = *reinterpret_cast<const uint4*>(kb + 8);
        vr0 = *reinterpret_cast<const uint4*>(kb + 512);
        vr1 = *reinterpret_cast<const uint4*>(kb + 520);
      }
      *reinterpret_cast<uint4*>(&Ks[stok * LDK + schk * 16]) = kr0;
      *reinterpret_cast<uint4*>(&Ks[stok * LDK + schk * 16 + 8]) = kr1;
      unsigned int wv[8] = {vr0.x, vr0.y, vr0.z, vr0.w, vr1.x, vr1.y, vr1.z, vr1.w};
#pragma unroll
      for (int e = 0; e < 16; ++e)
        Vt[(schk * 16 + e) * LDK + stok] = (unsigned short)(wv[e >> 1] >> ((e & 1) * 16));
    }
    int meta = 0x10000;
    {
      int kk = k0 + lane;
      if (kk < 1800) {
        int base = bg * 1800 + kk;
        meta = tt[base] | (km[base] ? 0x10000 : 0);
      }
    }
    __syncthreads();

    floatx4 S[4];
#pragma unroll
    for (int nt = 0; nt < 4; ++nt) {
      const unsigned short* kb = Ks + (nt * 16 + mrow) * LDK + quad * 8;
      short8 b0 = *reinterpret_cast<const short8*>(kb);
      short8 b1 = *reinterpret_cast<const short8*>(kb + 32);
      floatx4 s = (floatx4){0.f, 0.f, 0.f, 0.f};
      s = __builtin_amdgcn_mfma_f32_16x16x32_bf16(af0, b0, s, 0, 0, 0);
      s = __builtin_amdgcn_mfma_f32_16x16x32_bf16(af1, b1, s, 0, 0, 0);
      S[nt] = s;
    }
    int mcol[4];
#pragma unroll
    for (int nt = 0; nt < 4; ++nt)
      mcol[nt] = __builtin_amdgcn_ds_bpermute((nt * 16 + mrow) << 2, meta);
    float sv[4][4];
#pragma unroll
    for (int nt = 0; nt < 4; ++nt) {
      int tk = mcol[nt] & 0xffff;
      int bad0 = mcol[nt] >> 16;
#pragma unroll
      for (int r = 0; r < 4; ++r) {
        float v = S[nt][r] * 0.125f;
        int ridx = (tq[r] - tk) & 31;
        v += __int_as_float(__builtin_amdgcn_ds_bpermute(ridx << 2, __float_as_int(relreg)));
        sv[nt][r] = (bad0 | (tk >= tq[r])) ? -1e30f : v;
      }
    }
#pragma unroll
    for (int r = 0; r < 4; ++r) {
      float rm = fmaxf(fmaxf(sv[0][r], sv[1][r]), fmaxf(sv[2][r], sv[3][r]));
#pragma unroll
      for (int d = 1; d < 16; d <<= 1) rm = fmaxf(rm, __shfl_xor(rm, d, 64));
      float nm = fmaxf(m[r], rm);
      float corr = __expf(m[r] - nm);
      float ps = 0.f;
      const int prow = (wave * 16 + quad * 4 + r) * LDK + mrow;
#pragma unroll
      for (int nt = 0; nt < 4; ++nt) {
        float p = __expf(sv[nt][r] - nm);
        ps += p;
        Ps[prow + nt * 16] = f2bf(p);
      }
#pragma unroll
      for (int d = 1; d < 16; d <<= 1) ps += __shfl_xor(ps, d, 64);
      l[r] = l[r] * corr + ps;
      m[r] = nm;
#pragma unroll
      for (int nt = 0; nt < 4; ++nt) acc[nt][r] *= corr;
    }
    const unsigned short* pp = Ps + (wave * 16 + mrow) * LDK + quad * 8;
    short8 a0 = *reinterpret_cast<const short8*>(pp);
    short8 a1 = *reinterpret_cast<const short8*>(pp + 32);
#pragma unroll
    for (int nt = 0; nt < 4; ++nt) {
      const unsigned short* vb = Vt + (nt * 16 + mrow) * LDK + quad * 8;
      short8 b0 = *reinterpret_cast<const short8*>(vb);
      short8 b1 = *reinterpret_cast<const short8*>(vb + 32);
      acc[nt] = __builtin_amdgcn_mfma_f32_16x16x32_bf16(a0, b0, acc[nt], 0, 0, 0);
      acc[nt] = __builtin_amdgcn_mfma_f32_16x16x32_bf16(a1, b1, acc[nt], 0, 0, 0);
    }
  }

  __syncthreads();
  float* MA = (float*)SMEM;
  float* Ml = (float*)(SMEM + 64 * 68 * 2);
  float* Ll = Ml + 64;
  if (grp == 1) {
#pragma unroll
    for (int r = 0; r < 4; ++r) {
      int row = wave * 16 + quad * 4 + r;
#pragma unroll
      for (int nt = 0; nt < 4; ++nt)
        MA[row * 68 + nt * 16 + mrow] = acc[nt][r];
      if (mrow == 0) { Ml[row] = m[r]; Ll[row] = l[r]; }
    }
  }
  __syncthreads();
  if (grp == 0) {
#pragma unroll
    for (int r = 0; r < 4; ++r) {
      int row = wave * 16 + quad * 4 + r;
      float m1 = Ml[row], l1 = Ll[row];
      float M = fmaxf(m[r], m1);
      float c0 = __expf(m[r] - M), c1 = __expf(m1 - M);
      float invL = 1.f / (l[r] * c0 + l1 * c1);
      if (row < 60) {
        unsigned short* op = O + (size_t)(bg * 60 + row) * 512 + h * 64;
#pragma unroll
        for (int nt = 0; nt < 4; ++nt) {
          float o = (acc[nt][r] * c0 + MA[row * 68 + nt * 16 + mrow] * c1) * invL;
          op[nt * 16 + mrow] = f2bf(o);
        }
      }
    }
  }
}

// ---------------- VALU flash attention (self-attn, kLen=60) ----------------
#define QPB 32
#define QPW 8
__global__ __launch_bounds__(256) void attn2_kernel(
    const unsigned short* __restrict__ Qp, int qs,
    const unsigned short* __restrict__ Kp, int ks,
    const unsigned short* __restrict__ Vp, int vs,
    unsigned short* __restrict__ O, int os, int kLen,
    const unsigned char* __restrict__ kmask)
{
  const int bg = blockIdx.x >> 3;
  const int h  = blockIdx.x & 7;
  const int q0 = blockIdx.y * QPB;
  const int tid = threadIdx.x;
  const int wave = tid >> 6, lane = tid & 63;

  __shared__ float Qs[QPB][68];
  __shared__ float Ks[64][68];
  __shared__ float Vs[64][68];
  __shared__ float Ps[QPB][68];

  {
    int qr = tid >> 3, j = tid & 7;
    int q = q0 + qr;
    float f[8] = {0, 0, 0, 0, 0, 0, 0, 0};
    if (q < 60) {
      uint4 v = *reinterpret_cast<const uint4*>(Qp + (size_t)(bg * 60 + q) * qs + h * 64 + j * 8);
      f[0] = bflo(v.x); f[1] = bfhi(v.x); f[2] = bflo(v.y); f[3] = bfhi(v.y);
      f[4] = bflo(v.z); f[5] = bfhi(v.z); f[6] = bflo(v.w); f[7] = bfhi(v.w);
    }
#pragma unroll
    for (int e = 0; e < 8; ++e) Qs[qr][j * 8 + e] = f[e];
  }

  float m[QPW], l[QPW], acc[QPW];
#pragma unroll
  for (int i = 0; i < QPW; ++i) { m[i] = 0.f; l[i] = 1.f; acc[i] = 0.f; }

  const int std = tid >> 2;
  const int stj = tid & 3;

  for (int k0 = 0; k0 < kLen; k0 += 64) {
    __syncthreads();
    const bool sok = (k0 + std) < kLen;
    {
      const unsigned short* kb = Kp + ((size_t)bg * kLen + k0 + std) * ks + h * 64 + stj * 16;
      float f[16];
#pragma unroll
      for (int e = 0; e < 16; ++e) f[e] = 0.f;
      if (sok) {
        uint4 v0 = *reinterpret_cast<const uint4*>(kb);
        uint4 v1 = *reinterpret_cast<const uint4*>(kb + 8);
        f[0] = bflo(v0.x); f[1] = bfhi(v0.x); f[2]  = bflo(v0.y); f[3]  = bfhi(v0.y);
        f[4] = bflo(v0.z); f[5] = bfhi(v0.z); f[6]  = bflo(v0.w); f[7]  = bfhi(v0.w);
        f[8] = bflo(v1.x); f[9] = bfhi(v1.x); f[10] = bflo(v1.y); f[11] = bfhi(v1.y);
        f[12] = bflo(v1.z); f[13] = bfhi(v1.z); f[14] = bflo(v1.w); f[15] = bfhi(v1.w);
      }
#pragma unroll
      for (int e = 0; e < 16; ++e) Ks[stj * 16 + e][std] = f[e];
    }
    {
      const unsigned short* vb = Vp + ((size_t)bg * kLen + k0 + std) * vs + h * 64;
#pragma unroll
      for (int c = 0; c < 2; ++c) {
        int off = c * 32 + stj * 8;
        float f[8] = {0, 0, 0, 0, 0, 0, 0, 0};
        if (sok) {
          uint4 v = *reinterpret_cast<const uint4*>(vb + off);
          f[0] = bflo(v.x); f[1] = bfhi(v.x); f[2] = bflo(v.y); f[3] = bfhi(v.y);
          f[4] = bflo(v.z); f[5] = bfhi(v.z); f[6] = bflo(v.w); f[7] = bfhi(v.w);
        }
#pragma unroll
        for (int e = 0; e < 8; ++e) Vs[std][off + e] = f[e];
      }
    }
    const int kk = k0 + lane;
    const bool kok = kk < kLen;
    unsigned char kmv = 0;
    if (kok && kmask) kmv = kmask[(size_t)bg * kLen + kk];
    __syncthreads();

    float s[QPW];
#pragma unroll
    for (int i = 0; i < QPW; ++i) s[i] = 0.f;
    for (int d = 0; d < 64; ++d) {
      float kv = Ks[d][lane];
#pragma unroll
      for (int i = 0; i < QPW; ++i)
        s[i] = fmaf(Qs[wave * QPW + i][d], kv, s[i]);
    }

    const int kmax = min(64, kLen - k0);
#pragma unroll
    for (int i = 0; i < QPW; ++i) {
      float svv = s[i] * 0.125f;
      if (kmv || !kok) svv = -1e30f;
      float nm = fmaxf(m[i], wred_max(svv));
      float p = __expf(svv - nm);
      float ts = wred_sum(p);
      float corr = __expf(m[i] - nm);
      l[i] = l[i] * corr + ts;
      acc[i] *= corr;
      m[i] = nm;
      Ps[wave * QPW + i][lane] = p;
    }
    for (int k = 0; k < kmax; ++k) {
      float v = Vs[k][lane];
#pragma unroll
      for (int i = 0; i < QPW; ++i)
        acc[i] = fmaf(Ps[wave * QPW + i][k], v, acc[i]);
    }
  }

#pragma unroll
  for (int i = 0; i < QPW; ++i) {
    int q = q0 + wave * QPW + i;
    if (q < 60)
      O[(size_t)(bg * 60 + q) * os + h * 64 + lane] = f2bf(acc[i] / l[i]);
  }
}

// ---------------- residual add + LayerNorm (E=512), dual fp32+bf16 out ----------------
__global__ __launch_bounds__(256) void add_ln_kernel(
    const float* __restrict__ a, const float* __restrict__ b,
    const float* __restrict__ g, const float* __restrict__ be,
    float* __restrict__ o, unsigned short* __restrict__ ob)
{
  const int t = blockIdx.x;
  const int tid = threadIdx.x;
  const int wave = tid >> 6, lane = tid & 63;
  const size_t base = (size_t)t * 512;
  float v0 = a[base + tid] + b[base + tid];
  float v1 = a[base + 256 + tid] + b[base + 256 + tid];
  __shared__ float red[4];
  float s = wred_sum(v0 + v1);
  if (lane == 0) red[wave] = s;
  __syncthreads();
  float mean = (red[0] + red[1] + red[2] + red[3]) * (1.0f / 512.0f);
  float d0 = v0 - mean, d1 = v1 - mean;
  float vs = wred_sum(d0 * d0 + d1 * d1);
  __syncthreads();
  if (lane == 0) red[wave] = vs;
  __syncthreads();
  float var = (red[0] + red[1] + red[2] + red[3]) * (1.0f / 512.0f);
  float rstd = rsqrtf(var + 1e-5f);
  float r0 = d0 * rstd * g[tid] + be[tid];
  float r1 = d1 * rstd * g[256 + tid] + be[256 + tid];
  o[base + tid] = r0;
  o[base + 256 + tid] = r1;
  ob[base + tid] = f2bf(r0);
  ob[base + 256 + tid] = f2bf(r1);
}

// ---------------- embedding builders ----------------
__global__ __launch_bounds__(256) void build_traj_kernel(
    const float* __restrict__ tf, const int* __restrict__ ids,
    const float* __restrict__ Ww, unsigned short* __restrict__ traj)
{
  int idx = blockIdx.x * 256 + threadIdx.x;
  int tok = idx >> 9;
  int j = idx & 511;
  float v = (j < 256) ? tf[((size_t)tok << 8) + j] : Ww[(j - 256) * 51 + ids[tok]];
  traj[idx] = f2bf(v);
}

__global__ __launch_bounds__(256) void build_unk_kernel(
    const float* __restrict__ uf, const float* __restrict__ Ww,
    float* __restrict__ x, unsigned short* __restrict__ xb)
{
  int idx = blockIdx.x * 256 + threadIdx.x;
  int tok = idx >> 9;
  int j = idx & 511;
  float v = (j < 256) ? uf[((size_t)tok << 8) + j] : Ww[(j - 256) * 51 + 50];
  x[idx] = v;
  xb[idx] = f2bf(v);
}

// ---------------- final head ----------------
__global__ __launch_bounds__(64) void head_kernel(
    const float* __restrict__ x, const float* __restrict__ Wout, float* __restrict__ out)
{
  const int t = blockIdx.x;
  const int tid = threadIdx.x;
  __shared__ float xs[256];
  for (int i = tid; i < 256; i += 64) xs[i] = x[(size_t)t * 512 + 256 + i];
  __syncthreads();
  if (tid < 51) {
    const float* w = Wout + tid * 256;
    float s = 0.f;
    for (int k = 0; k < 256; ++k) s = fmaf(xs[k], w[k], s);
    out[t * 51 + tid] = s;
  }
}

// ---------------- orchestration ----------------
extern "C" void kernel_launch(void* const* d_in, const int* in_sizes, int n_in,
                              void* d_out, int out_size, void* d_ws, size_t ws_size,
                              hipStream_t stream) {
  const float* tf  = (const float*)d_in[0];
  const float* uf  = (const float*)d_in[1];
  const int*   ids = (const int*)d_in[2];
  const int*   tt  = (const int*)d_in[3];
  const int*   ut  = (const int*)d_in[4];
  const unsigned char* tm = (const unsigned char*)d_in[5];
  const unsigned char* um = (const unsigned char*)d_in[6];
  const float* Ww   = (const float*)d_in[8];
  const float* Wout = (const float*)d_in[9];
  const float* rpe  = (const float*)d_in[10];
  const float* saW  = (const float*)d_in[11];
  const float* sab  = (const float*)d_in[12];
  const float* saO  = (const float*)d_in[13];
  const float* saob = (const float*)d_in[14];
  const float* sag  = (const float*)d_in[15];
  const float* sabn = (const float*)d_in[16];
  const float* caW  = (const float*)d_in[17];
  const float* cab  = (const float*)d_in[18];
  const float* caO  = (const float*)d_in[19];
  const float* caob = (const float*)d_in[20];
  const float* cag  = (const float*)d_in[21];
  const float* cabn = (const float*)d_in[22];
  const float* f1   = (const float*)d_in[23];
  const float* fb1  = (const float*)d_in[24];
  const float* f2   = (const float*)d_in[25];
  const float* fb2  = (const float*)d_in[26];
  const float* fg   = (const float*)d_in[27];
  const float* fbn  = (const float*)d_in[28];

  // ---- workspace layout ----
  unsigned short* trajb = (unsigned short*)d_ws;         // 57600*512 bf16
  unsigned short* KVb   = trajb + (size_t)29491200;      // 57600*1024 bf16 (K|V token-major)
  unsigned short* qkvb  = KVb   + (size_t)58982400;      // 1920*1536 bf16
  unsigned short* hb    = qkvb  + (size_t)2949120;       // 1920*2048 bf16
  unsigned short* xb    = hb    + (size_t)3932160;       // 1920*512 bf16
  float* x    = (float*)(xb + (size_t)983040);           // 1920*512 fp32
  float* ybuf = x + (size_t)983040;                      // 1920*512 fp32
  unsigned short* wtail = (unsigned short*)(ybuf + (size_t)983040);  // byte 200,540,160

  // pre-converted all-layer weights region (48.2 MB) if ws allows; else rotating 2MB scratch
  const size_t NEED = (size_t)200540160 + (size_t)24117248 * 2;   // ~248.8 MB
  const bool pre = ws_size >= NEED;
  unsigned short* wsa  = wtail;                          // 5 x 786432  (sa_Wqkv)
  unsigned short* wsaO = wsa  + (size_t)3932160;         // 5 x 262144  (sa_Wo)
  unsigned short* wca  = wsaO + (size_t)1310720;         // 6 x 786432  (ca_Wqkv)
  unsigned short* wcaO = wca  + (size_t)4718592;         // 6 x 262144  (ca_Wo)
  unsigned short* wf1  = wcaO + (size_t)1572864;         // 6 x 1048576 (ffn_W1)
  unsigned short* wf2  = wf1  + (size_t)6291456;         // 6 x 1048576 (ffn_W2)
  unsigned short* wconv = wtail;                         // fallback rotating scratch (2 MB)

  if (pre) {
    conv_kernel<<<dim3(3840), dim3(256), 0, stream>>>(saW, wsa, 3932160);
    conv_kernel<<<dim3(1280), dim3(256), 0, stream>>>(saO, wsaO, 1310720);
    conv_kernel<<<dim3(4608), dim3(256), 0, stream>>>(caW, wca, 4718592);
    conv_kernel<<<dim3(1536), dim3(256), 0, stream>>>(caO, wcaO, 1572864);
    conv_kernel<<<dim3(6144), dim3(256), 0, stream>>>(f1, wf1, 6291456);
    conv_kernel<<<dim3(6144), dim3(256), 0, stream>>>(f2, wf2, 6291456);
  }

  build_traj_kernel<<<dim3(115200), dim3(256), 0, stream>>>(tf, ids, Ww, trajb);
  build_unk_kernel<<<dim3(3840), dim3(256), 0, stream>>>(uf, Ww, x, xb);

  for (int l = 0; l < 6; ++l) {
    if (l > 0) {
      int sl = l - 1;
      const unsigned short* wq;
      if (pre) wq = wsa + (size_t)sl * 786432;
      else {
        conv_kernel<<<dim3(768), dim3(256), 0, stream>>>(saW + (size_t)sl * 786432, wconv, 786432);
        wq = wconv;
      }
      gemm_mfma<<<dim3(12, 15), dim3(256), 0, stream>>>(
          xb, 512, wq, 512, sab + sl * 1536, qkvb, 1536, 512, 0, 1);
      attn2_kernel<<<dim3(256, 2), dim3(256), 0, stream>>>(
          qkvb, 1536, qkvb + 512, 1536, qkvb + 1024, 1536, hb, 512, 60, um);
      const unsigned short* wo;
      if (pre) wo = wsaO + (size_t)sl * 262144;
      else {
        conv_kernel<<<dim3(256), dim3(256), 0, stream>>>(saO + (size_t)sl * 262144, wconv, 262144);
        wo = wconv;
      }
      gemm_mfma<<<dim3(4, 15), dim3(256), 0, stream>>>(
          hb, 512, wo, 512, saob + sl * 512, ybuf, 512, 512, 0, 0);
      add_ln_kernel<<<dim3(1920), dim3(256), 0, stream>>>(x, ybuf, sag + sl * 512, sabn + sl * 512, x, xb);
    }
    const unsigned short* wqkv;
    if (pre) wqkv = wca + (size_t)l * 786432;
    else {
      conv_kernel<<<dim3(768), dim3(256), 0, stream>>>(caW + (size_t)l * 786432, wconv, 786432);
      wqkv = wconv;
    }
    // cross-attn K|V: [57600,512] @ [1024,512]^T -> [57600,1024] bf16 (N-fast grid)
    gemm_mfma<<<dim3(8, 450), dim3(256), 0, stream>>>(
        trajb, 512, wqkv + 262144, 512, cab + l * 1536 + 512, KVb, 1024, 512, 0, 1);
    // cross-attn Q: [1920,512]
    gemm_mfma<<<dim3(4, 15), dim3(256), 0, stream>>>(
        xb, 512, wqkv, 512, cab + l * 1536, qkvb, 512, 512, 0, 1);
    attn_mfma_kernel<<<dim3(256), dim3(512), 0, stream>>>(
        qkvb, KVb, hb, tt, ut, tm, rpe + l * 256);
    const unsigned short* wco;
    if (pre) wco = wcaO + (size_t)l * 262144;
    else {
      conv_kernel<<<dim3(256), dim3(256), 0, stream>>>(caO + (size_t)l * 262144, wconv, 262144);
      wco = wconv;
    }
    gemm_mfma<<<dim3(4, 15), dim3(256), 0, stream>>>(
        hb, 512, wco, 512, caob + l * 512, ybuf, 512, 512, 0, 0);
    add_ln_kernel<<<dim3(1920), dim3(256), 0, stream>>>(x, ybuf, cag + l * 512, cabn + l * 512, x, xb);
    // FFN1 + exact GELU
    const unsigned short* w1;
    if (pre) w1 = wf1 + (size_t)l * 1048576;
    else {
      conv_kernel<<<dim3(1024), dim3(256), 0, stream>>>(f1 + (size_t)l * 1048576, wconv, 1048576);
      w1 = wconv;
    }
    gemm_mfma<<<dim3(16, 15), dim3(256), 0, stream>>>(
        xb, 512, w1, 512, fb1 + l * 2048, hb, 2048, 512, 1, 1);
    // FFN2
    const unsigned short* w2;
    if (pre) w2 = wf2 + (size_t)l * 1048576;
    else {
      conv_kernel<<<dim3(1024), dim3(256), 0, stream>>>(f2 + (size_t)l * 1048576, wconv, 1048576);
      w2 = wconv;
    }
    gemm_mfma<<<dim3(4, 15), dim3(256), 0, stream>>>(
        hb, 2048, w2, 2048, fb2 + l * 512, ybuf, 512, 2048, 0, 0);
    add_ln_kernel<<<dim3(1920), dim3(256), 0, stream>>>(x, ybuf, fg + l * 512, fbn + l * 512, x, xb);
  }
  head_kernel<<<dim3(1920), dim3(64), 0, stream>>>(x, Wout, (float*)d_out);
}